// Round 2
// baseline (1913.612 us; speedup 1.0000x reference)
//
#include <hip/hip_runtime.h>
#include <math.h>

// DIEN: B=2048 T=100 D=64. fp32 correctness-first pipeline.
// Pipeline: prep(W1 fold) -> target/qproj -> GRU1 scan -> attention -> AUGRU scan -> aux -> MLP.

#define DEV __device__ __forceinline__

constexpr int BB = 2048;
constexpr int TT = 100;

DEV float sigmoidf_(float x) { return 1.0f / (1.0f + __expf(-x)); }
DEV float tanhf_(float x)    { return 1.0f - 2.0f / (__expf(2.0f * x) + 1.0f); }

// ---------------- prep: fold att_W1 into Wq/Wk/Wp; zero aux accumulator ----------------
__global__ void k_prep(const float* __restrict__ W1, float* Wq, float* Wk, float* Wp, float* aux_acc) {
    int i = blockIdx.x * 256 + threadIdx.x;  // 16 blocks x 256 = 4096
    if (i < 4096) {
        int k = i >> 6, c = i & 63;
        float a  = W1[k * 64 + c];
        float bb = W1[(64 + k) * 64 + c];
        float cc = W1[(128 + k) * 64 + c];
        float dd = W1[(192 + k) * 64 + c];
        Wq[i] = a + cc;   // qe @ (W1a + W1c)
        Wk[i] = bb - cc;  // keys @ (W1b - W1c)
        Wp[i] = dd;       // (qe*keys) @ W1d
    }
    if (blockIdx.x == 0 && threadIdx.x == 0) { aux_acc[0] = 0.0f; aux_acc[1] = 0.0f; }
}

// ---------------- target gather + qproj = q@Wq + b1 ----------------
__global__ __launch_bounds__(64)
void k_target(const int* __restrict__ item, const float* __restrict__ emb_item,
              const float* __restrict__ Wq, const float* __restrict__ b1,
              float* target, float* qproj) {
    int b = blockIdx.x, c = threadIdx.x;
    __shared__ float q[64];
    int idx = item[b];
    float tv = emb_item[(size_t)idx * 64 + c];
    target[b * 64 + c] = tv;
    q[c] = tv;
    __syncthreads();
    float acc = b1[c];
#pragma unroll
    for (int k = 0; k < 64; ++k) acc = fmaf(q[k], Wq[k * 64 + c], acc);
    qproj[b * 64 + c] = acc;
}

// ---------------- GRU / AUGRU scan. 8 batch rows per block, 256 blocks. ----------------
// Weights transposed in LDS with XOR-swizzled k-groups so the 64-lane ds_read_b128 of a
// weight column-slice spreads over all 8 bank-groups (else stride-64 floats => 1 group).
template <int MODE>  // 0 = GRU1 (writes seq_h), 1 = AUGRU (uses scores, writes final_state)
__global__ __launch_bounds__(256, 1)
void k_scan(const int* __restrict__ seq_idx, const float* __restrict__ emb,
            const float* __restrict__ Wx, const float* __restrict__ Wh,
            const float* __restrict__ bias, const int* __restrict__ hist_len,
            const float* __restrict__ scores, float* __restrict__ seq_out,
            float* __restrict__ final_out) {
    __shared__ __align__(16) float WxT[192 * 64];
    __shared__ __align__(16) float WhT[192 * 64];
    __shared__ __align__(16) float EH[2][512];  // [0]=input e, [1]=h state  (8 rows x 64)
    __shared__ __align__(16) float GZ[512], GR[512], GXH[512], GHH[512];
    __shared__ int hist_s[8];

    const int tid = threadIdx.x;
    const int b0  = blockIdx.x * 8;

    // stage weights (transposed + swizzled): element (k,c) -> WxT[c*64 + 4*((k>>2)^(c&7)) + (k&3)]
    for (int i = tid; i < 12288; i += 256) {
        int k = i / 192, c = i - k * 192;
        int pos = c * 64 + (((k >> 2) ^ (c & 7)) << 2) + (k & 3);
        WxT[pos] = Wx[i];
        WhT[pos] = Wh[i];
    }
    for (int i = tid; i < 512; i += 256) EH[1][i] = 0.0f;
    if (tid < 8) hist_s[tid] = hist_len[b0 + tid];
    __syncthreads();

    const int c  = tid;  // GEMM column (active for tid<192)
    const int cb = c & 7;
    float bx = (c < 192) ? bias[c] : 0.0f;
    const float4* WxT4 = (const float4*)WxT;
    const float4* WhT4 = (const float4*)WhT;
    const float4* E4   = (const float4*)EH[0];
    const float4* H4   = (const float4*)EH[1];

    for (int t = 0; t < TT; ++t) {
        // gather this step's input rows (8 x 64)
        for (int i = tid; i < 512; i += 256) {
            int r = i >> 6, kk = i & 63;
            float v;
            if (MODE == 0) {
                int idx = seq_idx[(b0 + r) * TT + t];
                v = emb[(size_t)idx * 64 + kk];
            } else {
                v = emb[(size_t)(b0 + r) * (TT * 64) + t * 64 + kk];
            }
            EH[0][i] = v;
        }
        __syncthreads();  // A

        if (c < 192) {
            float accx[8], acch[8];
#pragma unroll
            for (int r = 0; r < 8; ++r) { accx[r] = bx; acch[r] = 0.0f; }
            const int cbase = c * 16;
            for (int i = 0; i < 16; ++i) {
                float4 wx = WxT4[cbase + (i ^ cb)];  // k-group i (swizzle-inverted)
                float4 wh = WhT4[cbase + (i ^ cb)];
#pragma unroll
                for (int r = 0; r < 8; ++r) {
                    float4 e = E4[r * 16 + i];
                    float4 h = H4[r * 16 + i];
                    accx[r] = fmaf(e.x, wx.x, accx[r]); accx[r] = fmaf(e.y, wx.y, accx[r]);
                    accx[r] = fmaf(e.z, wx.z, accx[r]); accx[r] = fmaf(e.w, wx.w, accx[r]);
                    acch[r] = fmaf(h.x, wh.x, acch[r]); acch[r] = fmaf(h.y, wh.y, acch[r]);
                    acch[r] = fmaf(h.z, wh.z, acch[r]); acch[r] = fmaf(h.w, wh.w, acch[r]);
                }
            }
            int p = c >> 6, d = c & 63;
            if (p == 0) {
#pragma unroll
                for (int r = 0; r < 8; ++r) GZ[r * 64 + d] = accx[r] + acch[r];
            } else if (p == 1) {
#pragma unroll
                for (int r = 0; r < 8; ++r) GR[r * 64 + d] = accx[r] + acch[r];
            } else {
#pragma unroll
                for (int r = 0; r < 8; ++r) { GXH[r * 64 + d] = accx[r]; GHH[r * 64 + d] = acch[r]; }
            }
        }
        __syncthreads();  // G

        // gate phase: each thread owns 2 consecutive h-dims of one row
        {
            int u = tid << 1;
            int r = u >> 6;
            int brow = b0 + r;
            bool valid = (t < hist_s[r]);
            float a01 = 1.0f;
            if (MODE == 1) a01 = scores[brow * TT + t];
            float2 vz  = *(const float2*)&GZ[u];
            float2 vr  = *(const float2*)&GR[u];
            float2 vxh = *(const float2*)&GXH[u];
            float2 vhh = *(const float2*)&GHH[u];
            float2 hold = *(const float2*)&EH[1][u];
            float z0 = sigmoidf_(vz.x) * a01, z1 = sigmoidf_(vz.y) * a01;
            float r0 = sigmoidf_(vr.x),       r1 = sigmoidf_(vr.y);
            float c0 = tanhf_(fmaf(r0, vhh.x, vxh.x));
            float c1 = tanhf_(fmaf(r1, vhh.y, vxh.y));
            float h0 = valid ? fmaf(z0, c0 - hold.x, hold.x) : hold.x;  // h + z*(cand-h)
            float h1 = valid ? fmaf(z1, c1 - hold.y, hold.y) : hold.y;
            *(float2*)&EH[1][u] = make_float2(h0, h1);
            if (MODE == 0) {
                int d = u & 63;
                *(float2*)&seq_out[(size_t)brow * (TT * 64) + t * 64 + d] = make_float2(h0, h1);
            }
        }
        __syncthreads();  // B
    }

    if (MODE == 1) {
        for (int i = tid; i < 512; i += 256) {
            int r = i >> 6, d = i & 63;
            final_out[(b0 + r) * 64 + d] = EH[1][i];
        }
    }
}

// ---------------- attention: per-b block; factored MLP + masked softmax ----------------
__global__ __launch_bounds__(256)
void k_attn(const float* __restrict__ seq_h, const float* __restrict__ target,
            const float* __restrict__ qproj, const int* __restrict__ seq_idx,
            const float* __restrict__ W2g, const float* __restrict__ b2g,
            const float* __restrict__ W3g, const float* __restrict__ b3g,
            const float* __restrict__ Wkg, const float* __restrict__ Wpg,
            float* __restrict__ scores) {
    int b = blockIdx.x, tid = threadIdx.x;
    __shared__ float Wk_s[64 * 64], Wp_s[64 * 64], W2_s[64 * 16];
    __shared__ float q_s[64], qp_s[64];
    __shared__ float keys_s[4][64], pk_s[4][64], h1_s[4][64], h2_s[4][16];
    __shared__ float logit_s[104];
    __shared__ float invsum_s;

    for (int i = tid; i < 4096; i += 256) { Wk_s[i] = Wkg[i]; Wp_s[i] = Wpg[i]; }
    for (int i = tid; i < 1024; i += 256) W2_s[i] = W2g[i];
    if (tid < 64) { q_s[tid] = target[b * 64 + tid]; qp_s[tid] = qproj[b * 64 + tid]; }
    __syncthreads();

    const int tq = tid >> 6, cc = tid & 63;
    for (int tg = 0; tg < 25; ++tg) {
        int t = tg * 4 + tq;
        float kv = seq_h[(size_t)b * (TT * 64) + t * 64 + cc];
        keys_s[tq][cc] = kv;
        pk_s[tq][cc]   = kv * q_s[cc];
        __syncthreads();
        float acc = qp_s[cc];  // includes b1
        for (int k = 0; k < 64; ++k) {
            acc = fmaf(keys_s[tq][k], Wk_s[k * 64 + cc], acc);
            acc = fmaf(pk_s[tq][k],   Wp_s[k * 64 + cc], acc);
        }
        h1_s[tq][cc] = sigmoidf_(acc);
        __syncthreads();
        if (tid < 64) {
            int q4 = tid >> 4, j = tid & 15;
            float a2 = b2g[j];
#pragma unroll
            for (int k = 0; k < 64; ++k) a2 = fmaf(h1_s[q4][k], W2_s[k * 16 + j], a2);
            h2_s[q4][j] = sigmoidf_(a2);
        }
        __syncthreads();
        if (tid < 4) {
            float a3 = b3g[0];
#pragma unroll
            for (int j = 0; j < 16; ++j) a3 = fmaf(h2_s[tid][j], W3g[j], a3);
            int ttt = tg * 4 + tid;
            bool m = (seq_idx[b * TT + ttt] != 0);
            logit_s[ttt] = m ? a3 : -1e9f;
        }
        __syncthreads();
    }
    if (tid == 0) {
        float mx = -1e30f;
        for (int t = 0; t < TT; ++t) mx = fmaxf(mx, logit_s[t]);
        float s = 0.0f;
        for (int t = 0; t < TT; ++t) { float e = __expf(logit_s[t] - mx); logit_s[t] = e; s += e; }
        invsum_s = 1.0f / s;
    }
    __syncthreads();
    if (tid < TT) scores[b * TT + tid] = logit_s[tid] * invsum_s;
}

// ---------------- aux loss: one wave per batch row ----------------
__global__ __launch_bounds__(64)
void k_aux(const float* __restrict__ seq_h, const int* __restrict__ seq_idx,
           const int* __restrict__ neg_idx, const float* __restrict__ emb_item,
           const float* __restrict__ emb_neg, float* aux_acc) {
    int b = blockIdx.x, l = threadIdx.x;
    float num = 0.0f;
    float den = 0.0f;
    for (int t = 0; t < TT - 1; ++t) {
        int ip = seq_idx[b * TT + t + 1];
        int in_ = neg_idx[b * TT + t + 1];
        float h = seq_h[(size_t)b * (TT * 64) + t * 64 + l];
        float dp = h * emb_item[(size_t)ip * 64 + l];
        float dn = h * emb_neg[(size_t)in_ * 64 + l];
#pragma unroll
        for (int s = 32; s; s >>= 1) { dp += __shfl_xor(dp, s); dn += __shfl_xor(dn, s); }
        if (l == 0 && ip != 0) {
            float pp = sigmoidf_(dp), pn = sigmoidf_(dn);
            num += __logf(pp + 1e-8f) + __logf(1.0f - pn + 1e-8f);
            den += 1.0f;
        }
    }
    if (l == 0) {
        atomicAdd(&aux_acc[0], num);
        atomicAdd(&aux_acc[1], den);
    }
}

// ---------------- final MLP (BN + 3x dice FFN + sigmoid head) + aux write ----------------
__global__ __launch_bounds__(256)
void k_mlp(const float* __restrict__ final_state, const float* __restrict__ target,
           const float* __restrict__ dense, const int* __restrict__ sparse,
           const float* __restrict__ emb_other,
           const float* __restrict__ bng, const float* __restrict__ bnb,
           const float* __restrict__ W0, const float* __restrict__ bb0, const float* __restrict__ al0,
           const float* __restrict__ W1, const float* __restrict__ bb1, const float* __restrict__ al1,
           const float* __restrict__ W2, const float* __restrict__ bb2, const float* __restrict__ al2,
           const float* __restrict__ Wo, const float* __restrict__ bo,
           const float* __restrict__ aux_acc, float* __restrict__ out) {
    const float inv1 = 0.9995003747f;  // 1/sqrt(1+BN_EPS)
    int tid = threadIdx.x, b0 = blockIdx.x * 8;
    __shared__ float x_s[8][200], h1_s[8][256], h2_s[8][128], h3_s[8][64];

    for (int i = tid; i < 8 * 200; i += 256) {
        int r = i / 200, cc = i - r * 200, b = b0 + r;
        float v;
        if (cc < 64)       v = final_state[b * 64 + cc];
        else if (cc < 128) v = target[b * 64 + cc - 64];
        else if (cc < 136) v = dense[b * 8 + cc - 128];
        else if (cc < 168) v = emb_other[(size_t)sparse[b * 2 + 0] * 32 + (cc - 136)];
        else               v = emb_other[(size_t)10000 * 32 + (size_t)sparse[b * 2 + 1] * 32 + (cc - 168)];
        x_s[r][cc] = fmaf(bng[cc] * inv1, v, bnb[cc]);
    }
    __syncthreads();
    {   // L1: 200 -> 256, dice
        int r = tid >> 5, cb = tid & 31;
        float acc[8];
#pragma unroll
        for (int j = 0; j < 8; ++j) acc[j] = bb0[cb + 32 * j];
        for (int k = 0; k < 200; ++k) {
            float xv = x_s[r][k];
#pragma unroll
            for (int j = 0; j < 8; ++j) acc[j] = fmaf(xv, W0[k * 256 + cb + 32 * j], acc[j]);
        }
#pragma unroll
        for (int j = 0; j < 8; ++j) {
            float y = acc[j];
            float p = sigmoidf_(y * inv1);
            h1_s[r][cb + 32 * j] = y * (p + (1.0f - p) * al0[cb + 32 * j]);
        }
    }
    __syncthreads();
    {   // L2: 256 -> 128, dice
        int r = tid >> 5, cb = tid & 31;
        float acc[4];
#pragma unroll
        for (int j = 0; j < 4; ++j) acc[j] = bb1[cb + 32 * j];
        for (int k = 0; k < 256; ++k) {
            float xv = h1_s[r][k];
#pragma unroll
            for (int j = 0; j < 4; ++j) acc[j] = fmaf(xv, W1[k * 128 + cb + 32 * j], acc[j]);
        }
#pragma unroll
        for (int j = 0; j < 4; ++j) {
            float y = acc[j];
            float p = sigmoidf_(y * inv1);
            h2_s[r][cb + 32 * j] = y * (p + (1.0f - p) * al1[cb + 32 * j]);
        }
    }
    __syncthreads();
    {   // L3: 128 -> 64, dice
        int r = tid >> 5, cb = tid & 31;
        float acc[2] = {bb2[cb], bb2[cb + 32]};
        for (int k = 0; k < 128; ++k) {
            float xv = h2_s[r][k];
            acc[0] = fmaf(xv, W2[k * 64 + cb], acc[0]);
            acc[1] = fmaf(xv, W2[k * 64 + cb + 32], acc[1]);
        }
#pragma unroll
        for (int j = 0; j < 2; ++j) {
            float y = acc[j];
            float p = sigmoidf_(y * inv1);
            h3_s[r][cb + 32 * j] = y * (p + (1.0f - p) * al2[cb + 32 * j]);
        }
    }
    __syncthreads();
    {   // head: 64 -> 1 sigmoid
        int r = tid >> 5, l = tid & 31;
        float v = h3_s[r][l] * Wo[l] + h3_s[r][l + 32] * Wo[l + 32];
#pragma unroll
        for (int s = 16; s; s >>= 1) v += __shfl_xor(v, s, 32);
        if (l == 0) out[b0 + r] = sigmoidf_(v + bo[0]);
    }
    if (blockIdx.x == 0 && tid == 0) {
        out[BB] = -aux_acc[0] / (aux_acc[1] + 1e-8f);
    }
}

extern "C" void kernel_launch(void* const* d_in, const int* in_sizes, int n_in,
                              void* d_out, int out_size, void* d_ws, size_t ws_size,
                              hipStream_t stream) {
    (void)in_sizes; (void)n_in; (void)out_size; (void)ws_size;
    const float* dense    = (const float*)d_in[0];
    const int*   sparse   = (const int*)d_in[1];
    const int*   seq_in   = (const int*)d_in[2];
    const int*   neg_in   = (const int*)d_in[3];
    const int*   item_in  = (const int*)d_in[4];
    const int*   hist     = (const int*)d_in[5];
    const float* emb_item = (const float*)d_in[6];
    const float* emb_neg  = (const float*)d_in[7];
    const float* emb_oth  = (const float*)d_in[8];
    const float* g1Wx = (const float*)d_in[9];
    const float* g1Wh = (const float*)d_in[10];
    const float* g1b  = (const float*)d_in[11];
    const float* aW1  = (const float*)d_in[12];
    const float* ab1  = (const float*)d_in[13];
    const float* aW2  = (const float*)d_in[14];
    const float* ab2  = (const float*)d_in[15];
    const float* aW3  = (const float*)d_in[16];
    const float* ab3  = (const float*)d_in[17];
    const float* g2Wx = (const float*)d_in[18];
    const float* g2Wh = (const float*)d_in[19];
    const float* g2b  = (const float*)d_in[20];
    const float* bng  = (const float*)d_in[21];
    const float* bnb  = (const float*)d_in[22];
    const float* W0   = (const float*)d_in[23];
    const float* b0f  = (const float*)d_in[24];
    const float* a0f  = (const float*)d_in[25];
    const float* W1f  = (const float*)d_in[26];
    const float* b1f  = (const float*)d_in[27];
    const float* a1f  = (const float*)d_in[28];
    const float* W2f  = (const float*)d_in[29];
    const float* b2f  = (const float*)d_in[30];
    const float* a2f  = (const float*)d_in[31];
    const float* Wo   = (const float*)d_in[32];
    const float* bo   = (const float*)d_in[33];

    float* ws          = (float*)d_ws;
    float* seq_h       = ws;                      // B*T*64 = 13,107,200 floats
    float* scores      = seq_h + 13107200;        // B*T
    float* target      = scores + 204800;         // B*64
    float* qproj       = target + 131072;         // B*64
    float* final_state = qproj + 131072;          // B*64
    float* Wq          = final_state + 131072;    // 4096
    float* Wk          = Wq + 4096;
    float* Wp          = Wk + 4096;
    float* aux_acc     = Wp + 4096;               // 2  (total ~54.9 MB)

    k_prep<<<16, 256, 0, stream>>>(aW1, Wq, Wk, Wp, aux_acc);
    k_target<<<BB, 64, 0, stream>>>(item_in, emb_item, Wq, ab1, target, qproj);
    k_scan<0><<<256, 256, 0, stream>>>(seq_in, emb_item, g1Wx, g1Wh, g1b, hist, nullptr, seq_h, nullptr);
    k_attn<<<BB, 256, 0, stream>>>(seq_h, target, qproj, seq_in, aW2, ab2, aW3, ab3, Wk, Wp, scores);
    k_scan<1><<<256, 256, 0, stream>>>(nullptr, seq_h, g2Wx, g2Wh, g2b, hist, scores, nullptr, final_state);
    k_aux<<<BB, 64, 0, stream>>>(seq_h, seq_in, neg_in, emb_item, emb_neg, aux_acc);
    k_mlp<<<256, 256, 0, stream>>>(final_state, target, dense, sparse, emb_oth, bng, bnb,
                                   W0, b0f, a0f, W1f, b1f, a1f, W2f, b2f, a2f, Wo, bo,
                                   aux_acc, (float*)d_out);
}

// Round 3
// 884.844 us; speedup vs baseline: 2.1627x; 2.1627x over previous
//
#include <hip/hip_runtime.h>
#include <math.h>

// DIEN: B=2048 T=100 D=64.
// Round 3: MFMA-based GRU/AUGRU scans (bf16 matmul, fp32 recurrence in registers).
// Pipeline: prep(W1 fold) + prepW(pack Wx/Wh B-frags) -> target/qproj ->
//           GRU1 scan(MFMA) -> attention -> AUGRU scan(MFMA) -> aux -> MLP.

#define DEV __device__ __forceinline__

constexpr int BB = 2048;
constexpr int TT = 100;

typedef __attribute__((ext_vector_type(8))) short bf16x8;
typedef __attribute__((ext_vector_type(4))) float f32x4;

#define MFMA16(a, b, c) __builtin_amdgcn_mfma_f32_16x16x32_bf16(a, b, c, 0, 0, 0)

DEV float sigmoidf_(float x) { return 1.0f / (1.0f + __expf(-x)); }
DEV float tanhf_(float x)    { return 1.0f - 2.0f / (__expf(2.0f * x) + 1.0f); }
DEV short f2bf(float f) {  // fp32 -> bf16 bits, round-to-nearest-even
    unsigned u = __float_as_uint(f);
    u = (u + 0x7FFFu + ((u >> 16) & 1u)) >> 16;
    return (short)u;
}

// ---------------- prep: fold att_W1 into Wq/Wk/Wp; zero aux accumulator ----------------
__global__ void k_prep(const float* __restrict__ W1, float* Wq, float* Wk, float* Wp, float* aux_acc) {
    int i = blockIdx.x * 256 + threadIdx.x;  // 16 blocks x 256 = 4096
    if (i < 4096) {
        int k = i >> 6, c = i & 63;
        float a  = W1[k * 64 + c];
        float bb = W1[(64 + k) * 64 + c];
        float cc = W1[(128 + k) * 64 + c];
        float dd = W1[(192 + k) * 64 + c];
        Wq[i] = a + cc;   // qe @ (W1a + W1c)
        Wk[i] = bb - cc;  // keys @ (W1b - W1c)
        Wp[i] = dd;       // (qe*keys) @ W1d
    }
    if (blockIdx.x == 0 && threadIdx.x == 0) { aux_acc[0] = 0.0f; aux_acc[1] = 0.0f; }
}

// ---------------- prepW: pack GRU weights (64x192 fp32) into bf16 MFMA B-fragments ----
// frag f = n*2+kt (n: 16-col tile 0..11, kt: 32-k tile 0..1); lane l elem i holds
// W[kt*32 + (l>>4)*8 + i][n*16 + (l&15)]. Layout out[f*512 + l*8 + i].
__global__ __launch_bounds__(256)
void k_prepW(const float* __restrict__ Wa, const float* __restrict__ Wb,
             const float* __restrict__ Wc, const float* __restrict__ Wd,
             short* __restrict__ oa, short* __restrict__ ob,
             short* __restrict__ oc, short* __restrict__ od) {
    const float* W; short* o;
    switch (blockIdx.y) {
        case 0:  W = Wa; o = oa; break;
        case 1:  W = Wb; o = ob; break;
        case 2:  W = Wc; o = oc; break;
        default: W = Wd; o = od; break;
    }
    int d = blockIdx.x * 256 + threadIdx.x;  // 48 blocks -> 12288
    int frag = d >> 9, l = (d >> 3) & 63, i = d & 7;
    int n = frag >> 1, kt = frag & 1;
    int k = kt * 32 + ((l >> 4) << 3) + i;
    int c = (n << 4) + (l & 15);
    o[d] = f2bf(W[k * 192 + c]);
}

// ---------------- target gather + qproj = q@Wq + b1 ----------------
__global__ __launch_bounds__(64)
void k_target(const int* __restrict__ item, const float* __restrict__ emb_item,
              const float* __restrict__ Wq, const float* __restrict__ b1,
              float* target, float* qproj) {
    int b = blockIdx.x, c = threadIdx.x;
    __shared__ float q[64];
    int idx = item[b];
    float tv = emb_item[(size_t)idx * 64 + c];
    target[b * 64 + c] = tv;
    q[c] = tv;
    __syncthreads();
    float acc = b1[c];
#pragma unroll
    for (int k = 0; k < 64; ++k) acc = fmaf(q[k], Wq[k * 64 + c], acc);
    qproj[b * 64 + c] = acc;
}

// ---------------- MFMA GRU / AUGRU scan. 8 batch rows per block, 256 blocks. ----------
// Per step: [e | h] @ [Wx ; Wh] via 12 mfma_16x16x32_bf16 per wave.
// Wave w owns N-tiles {w, w+4, w+8} => each lane's C frag holds z/r/hh for the SAME
// (row, col): gates fully in registers. h recurrence kept in fp32 regs; bf16 copy of h
// double-buffered in swizzled LDS for the next step's A-fragment. One barrier/step.
template <int MODE>  // 0 = GRU1 (gather emb, write seq_h), 1 = AUGRU (read seq_h, scores, write final)
__global__ __launch_bounds__(256, 1)
void k_scan(const int* __restrict__ seq_idx, const float* __restrict__ src,
            const short* __restrict__ WxB, const short* __restrict__ WhB,
            const float* __restrict__ bias, const int* __restrict__ hist_len,
            const float* __restrict__ scores,
            float* __restrict__ seq_out, float* __restrict__ final_out) {
    __shared__ short hA[2][1024];  // [buf][row*64 + swz(kb,row)*8 + i], bf16 bits

    const int tid  = threadIdx.x;
    const int w    = tid >> 6;       // wave id 0..3
    const int lane = tid & 63;
    const int lr   = lane & 15;      // A-frag row / C-frag col-index
    const int kg   = lane >> 4;      // A-frag k-group / C-frag row-quad
    const int b0   = blockIdx.x * 8;

    for (int i = tid; i < 2048; i += 256) ((short*)hA)[i] = 0;

    // B-fragments in registers (constant across the whole scan)
    bf16x8 bx[3][2], bh[3][2];
#pragma unroll
    for (int n3 = 0; n3 < 3; ++n3) {
        int n = w + n3 * 4;
#pragma unroll
        for (int kt = 0; kt < 2; ++kt) {
            bx[n3][kt] = *(const bf16x8*)(WxB + (((n * 2 + kt) * 64 + lane) << 3));
            bh[n3][kt] = *(const bf16x8*)(WhB + (((n * 2 + kt) * 64 + lane) << 3));
        }
    }

    const int   c0  = (w << 4) + lr;          // gate column (0..63)
    const float bz  = bias[c0];
    const float brr = bias[64 + c0];
    const float bhb = bias[128 + c0];
    const int   qc  = kg & 1;                 // safe row-quad (dup for kg>=2)
    const bool  act = (kg < 2);               // lanes owning real C rows 0..7

    int   hist[4];
    float h[4] = {0.f, 0.f, 0.f, 0.f};
#pragma unroll
    for (int j = 0; j < 4; ++j) hist[j] = hist_len[b0 + qc * 4 + j];

    const int rload = (lr < 8) ? lr : 7;      // clamp: rows 8..15 are dummy
    float4 ec[4], en[4];
    float  scc[4] = {1.f, 1.f, 1.f, 1.f}, scn[4];

    {   // load e for t=0
        const float* eb;
        if (MODE == 0) { int idx = seq_idx[(b0 + rload) * TT]; eb = src + (size_t)idx * 64; }
        else           { eb = src + ((size_t)(b0 + rload) * TT) * 64; }
        ec[0] = *(const float4*)(eb + kg * 8);
        ec[1] = *(const float4*)(eb + kg * 8 + 4);
        ec[2] = *(const float4*)(eb + 32 + kg * 8);
        ec[3] = *(const float4*)(eb + 32 + kg * 8 + 4);
        if (MODE == 1) {
#pragma unroll
            for (int j = 0; j < 4; ++j) scc[j] = scores[(b0 + qc * 4 + j) * TT];
        }
    }
    __syncthreads();

    for (int t = 0; t < TT; ++t) {
        const int buf = t & 1;
        // A-fragments of h (swizzled LDS read; kb = kt*4+kg)
        const int so0 = lr * 64 + (((kg    ) ^ (lr & 7)) << 3);
        const int so1 = lr * 64 + (((4 + kg) ^ (lr & 7)) << 3);
        bf16x8 ha0 = *(const bf16x8*)&hA[buf][so0];
        bf16x8 ha1 = *(const bf16x8*)&hA[buf][so1];

        // prefetch next step's e (and scores)
        if (t < TT - 1) {
            const float* eb;
            if (MODE == 0) { int idx = seq_idx[(b0 + rload) * TT + t + 1]; eb = src + (size_t)idx * 64; }
            else           { eb = src + ((size_t)(b0 + rload) * TT + (t + 1)) * 64; }
            en[0] = *(const float4*)(eb + kg * 8);
            en[1] = *(const float4*)(eb + kg * 8 + 4);
            en[2] = *(const float4*)(eb + 32 + kg * 8);
            en[3] = *(const float4*)(eb + 32 + kg * 8 + 4);
            if (MODE == 1) {
#pragma unroll
                for (int j = 0; j < 4; ++j) scn[j] = scores[(b0 + qc * 4 + j) * TT + t + 1];
            }
        }

        // e -> bf16 A-fragments
        bf16x8 ea0, ea1;
        ea0[0] = f2bf(ec[0].x); ea0[1] = f2bf(ec[0].y); ea0[2] = f2bf(ec[0].z); ea0[3] = f2bf(ec[0].w);
        ea0[4] = f2bf(ec[1].x); ea0[5] = f2bf(ec[1].y); ea0[6] = f2bf(ec[1].z); ea0[7] = f2bf(ec[1].w);
        ea1[0] = f2bf(ec[2].x); ea1[1] = f2bf(ec[2].y); ea1[2] = f2bf(ec[2].z); ea1[3] = f2bf(ec[2].w);
        ea1[4] = f2bf(ec[3].x); ea1[5] = f2bf(ec[3].y); ea1[6] = f2bf(ec[3].z); ea1[7] = f2bf(ec[3].w);

        // 12 MFMA: z (e@Wx + h@Wh), r (same), h-tile split into x-part and h-part
        f32x4 az  = {0.f, 0.f, 0.f, 0.f};
        f32x4 ar  = {0.f, 0.f, 0.f, 0.f};
        f32x4 ahx = {0.f, 0.f, 0.f, 0.f};
        f32x4 ahh = {0.f, 0.f, 0.f, 0.f};
        az  = MFMA16(ea0, bx[0][0], az);  az  = MFMA16(ea1, bx[0][1], az);
        az  = MFMA16(ha0, bh[0][0], az);  az  = MFMA16(ha1, bh[0][1], az);
        ar  = MFMA16(ea0, bx[1][0], ar);  ar  = MFMA16(ea1, bx[1][1], ar);
        ar  = MFMA16(ha0, bh[1][0], ar);  ar  = MFMA16(ha1, bh[1][1], ar);
        ahx = MFMA16(ea0, bx[2][0], ahx); ahx = MFMA16(ea1, bx[2][1], ahx);
        ahh = MFMA16(ha0, bh[2][0], ahh); ahh = MFMA16(ha1, bh[2][1], ahh);

        if (act) {
#pragma unroll
            for (int j = 0; j < 4; ++j) {
                float a01  = (MODE == 1) ? scc[j] : 1.0f;
                float z    = sigmoidf_(az[j] + bz) * a01;
                float r    = sigmoidf_(ar[j] + brr);
                float cand = tanhf_(ahx[j] + bhb + r * ahh[j]);
                float hn   = h[j] + z * (cand - h[j]);      // (1-z)h + z*cand
                h[j] = (t < hist[j]) ? hn : h[j];
                int rr = qc * 4 + j;
                int sw = rr * 64 + ((((c0 >> 3)) ^ (rr & 7)) << 3) + (c0 & 7);
                hA[buf ^ 1][sw] = f2bf(h[j]);
                if (MODE == 0)
                    seq_out[((size_t)(b0 + rr) * TT + t) * 64 + c0] = h[j];
            }
        }
        if (t < TT - 1) {
#pragma unroll
            for (int q4 = 0; q4 < 4; ++q4) ec[q4] = en[q4];
            if (MODE == 1) {
#pragma unroll
                for (int j = 0; j < 4; ++j) scc[j] = scn[j];
            }
        }
        __syncthreads();
    }

    if (MODE == 1 && act) {
#pragma unroll
        for (int j = 0; j < 4; ++j) {
            int rr = qc * 4 + j;
            final_out[(b0 + rr) * 64 + c0] = h[j];
        }
    }
}

// ---------------- attention: per-b block; factored MLP + masked softmax ----------------
__global__ __launch_bounds__(256)
void k_attn(const float* __restrict__ seq_h, const float* __restrict__ target,
            const float* __restrict__ qproj, const int* __restrict__ seq_idx,
            const float* __restrict__ W2g, const float* __restrict__ b2g,
            const float* __restrict__ W3g, const float* __restrict__ b3g,
            const float* __restrict__ Wkg, const float* __restrict__ Wpg,
            float* __restrict__ scores) {
    int b = blockIdx.x, tid = threadIdx.x;
    __shared__ float Wk_s[64 * 64], Wp_s[64 * 64], W2_s[64 * 16];
    __shared__ float q_s[64], qp_s[64];
    __shared__ float keys_s[4][64], pk_s[4][64], h1_s[4][64], h2_s[4][16];
    __shared__ float logit_s[104];
    __shared__ float invsum_s;

    for (int i = tid; i < 4096; i += 256) { Wk_s[i] = Wkg[i]; Wp_s[i] = Wpg[i]; }
    for (int i = tid; i < 1024; i += 256) W2_s[i] = W2g[i];
    if (tid < 64) { q_s[tid] = target[b * 64 + tid]; qp_s[tid] = qproj[b * 64 + tid]; }
    __syncthreads();

    const int tq = tid >> 6, cc = tid & 63;
    for (int tg = 0; tg < 25; ++tg) {
        int t = tg * 4 + tq;
        float kv = seq_h[(size_t)b * (TT * 64) + t * 64 + cc];
        keys_s[tq][cc] = kv;
        pk_s[tq][cc]   = kv * q_s[cc];
        __syncthreads();
        float acc = qp_s[cc];  // includes b1
        for (int k = 0; k < 64; ++k) {
            acc = fmaf(keys_s[tq][k], Wk_s[k * 64 + cc], acc);
            acc = fmaf(pk_s[tq][k],   Wp_s[k * 64 + cc], acc);
        }
        h1_s[tq][cc] = sigmoidf_(acc);
        __syncthreads();
        if (tid < 64) {
            int q4 = tid >> 4, j = tid & 15;
            float a2 = b2g[j];
#pragma unroll
            for (int k = 0; k < 64; ++k) a2 = fmaf(h1_s[q4][k], W2_s[k * 16 + j], a2);
            h2_s[q4][j] = sigmoidf_(a2);
        }
        __syncthreads();
        if (tid < 4) {
            float a3 = b3g[0];
#pragma unroll
            for (int j = 0; j < 16; ++j) a3 = fmaf(h2_s[tid][j], W3g[j], a3);
            int ttt = tg * 4 + tid;
            bool m = (seq_idx[b * TT + ttt] != 0);
            logit_s[ttt] = m ? a3 : -1e9f;
        }
        __syncthreads();
    }
    if (tid == 0) {
        float mx = -1e30f;
        for (int t = 0; t < TT; ++t) mx = fmaxf(mx, logit_s[t]);
        float s = 0.0f;
        for (int t = 0; t < TT; ++t) { float e = __expf(logit_s[t] - mx); logit_s[t] = e; s += e; }
        invsum_s = 1.0f / s;
    }
    __syncthreads();
    if (tid < TT) scores[b * TT + tid] = logit_s[tid] * invsum_s;
}

// ---------------- aux loss: one wave per batch row ----------------
__global__ __launch_bounds__(64)
void k_aux(const float* __restrict__ seq_h, const int* __restrict__ seq_idx,
           const int* __restrict__ neg_idx, const float* __restrict__ emb_item,
           const float* __restrict__ emb_neg, float* aux_acc) {
    int b = blockIdx.x, l = threadIdx.x;
    float num = 0.0f;
    float den = 0.0f;
    for (int t = 0; t < TT - 1; ++t) {
        int ip = seq_idx[b * TT + t + 1];
        int in_ = neg_idx[b * TT + t + 1];
        float h = seq_h[(size_t)b * (TT * 64) + t * 64 + l];
        float dp = h * emb_item[(size_t)ip * 64 + l];
        float dn = h * emb_neg[(size_t)in_ * 64 + l];
#pragma unroll
        for (int s = 32; s; s >>= 1) { dp += __shfl_xor(dp, s); dn += __shfl_xor(dn, s); }
        if (l == 0 && ip != 0) {
            float pp = sigmoidf_(dp), pn = sigmoidf_(dn);
            num += __logf(pp + 1e-8f) + __logf(1.0f - pn + 1e-8f);
            den += 1.0f;
        }
    }
    if (l == 0) {
        atomicAdd(&aux_acc[0], num);
        atomicAdd(&aux_acc[1], den);
    }
}

// ---------------- final MLP (BN + 3x dice FFN + sigmoid head) + aux write ----------------
__global__ __launch_bounds__(256)
void k_mlp(const float* __restrict__ final_state, const float* __restrict__ target,
           const float* __restrict__ dense, const int* __restrict__ sparse,
           const float* __restrict__ emb_other,
           const float* __restrict__ bng, const float* __restrict__ bnb,
           const float* __restrict__ W0, const float* __restrict__ bb0, const float* __restrict__ al0,
           const float* __restrict__ W1, const float* __restrict__ bb1, const float* __restrict__ al1,
           const float* __restrict__ W2, const float* __restrict__ bb2, const float* __restrict__ al2,
           const float* __restrict__ Wo, const float* __restrict__ bo,
           const float* __restrict__ aux_acc, float* __restrict__ out) {
    const float inv1 = 0.9995003747f;  // 1/sqrt(1+BN_EPS)
    int tid = threadIdx.x, b0 = blockIdx.x * 8;
    __shared__ float x_s[8][200], h1_s[8][256], h2_s[8][128], h3_s[8][64];

    for (int i = tid; i < 8 * 200; i += 256) {
        int r = i / 200, cc = i - r * 200, b = b0 + r;
        float v;
        if (cc < 64)       v = final_state[b * 64 + cc];
        else if (cc < 128) v = target[b * 64 + cc - 64];
        else if (cc < 136) v = dense[b * 8 + cc - 128];
        else if (cc < 168) v = emb_other[(size_t)sparse[b * 2 + 0] * 32 + (cc - 136)];
        else               v = emb_other[(size_t)10000 * 32 + (size_t)sparse[b * 2 + 1] * 32 + (cc - 168)];
        x_s[r][cc] = fmaf(bng[cc] * inv1, v, bnb[cc]);
    }
    __syncthreads();
    {   // L1: 200 -> 256, dice
        int r = tid >> 5, cb = tid & 31;
        float acc[8];
#pragma unroll
        for (int j = 0; j < 8; ++j) acc[j] = bb0[cb + 32 * j];
        for (int k = 0; k < 200; ++k) {
            float xv = x_s[r][k];
#pragma unroll
            for (int j = 0; j < 8; ++j) acc[j] = fmaf(xv, W0[k * 256 + cb + 32 * j], acc[j]);
        }
#pragma unroll
        for (int j = 0; j < 8; ++j) {
            float y = acc[j];
            float p = sigmoidf_(y * inv1);
            h1_s[r][cb + 32 * j] = y * (p + (1.0f - p) * al0[cb + 32 * j]);
        }
    }
    __syncthreads();
    {   // L2: 256 -> 128, dice
        int r = tid >> 5, cb = tid & 31;
        float acc[4];
#pragma unroll
        for (int j = 0; j < 4; ++j) acc[j] = bb1[cb + 32 * j];
        for (int k = 0; k < 256; ++k) {
            float xv = h1_s[r][k];
#pragma unroll
            for (int j = 0; j < 4; ++j) acc[j] = fmaf(xv, W1[k * 128 + cb + 32 * j], acc[j]);
        }
#pragma unroll
        for (int j = 0; j < 4; ++j) {
            float y = acc[j];
            float p = sigmoidf_(y * inv1);
            h2_s[r][cb + 32 * j] = y * (p + (1.0f - p) * al1[cb + 32 * j]);
        }
    }
    __syncthreads();
    {   // L3: 128 -> 64, dice
        int r = tid >> 5, cb = tid & 31;
        float acc[2] = {bb2[cb], bb2[cb + 32]};
        for (int k = 0; k < 128; ++k) {
            float xv = h2_s[r][k];
            acc[0] = fmaf(xv, W2[k * 64 + cb], acc[0]);
            acc[1] = fmaf(xv, W2[k * 64 + cb + 32], acc[1]);
        }
#pragma unroll
        for (int j = 0; j < 2; ++j) {
            float y = acc[j];
            float p = sigmoidf_(y * inv1);
            h3_s[r][cb + 32 * j] = y * (p + (1.0f - p) * al2[cb + 32 * j]);
        }
    }
    __syncthreads();
    {   // head: 64 -> 1 sigmoid
        int r = tid >> 5, l = tid & 31;
        float v = h3_s[r][l] * Wo[l] + h3_s[r][l + 32] * Wo[l + 32];
#pragma unroll
        for (int s = 16; s; s >>= 1) v += __shfl_xor(v, s, 32);
        if (l == 0) out[b0 + r] = sigmoidf_(v + bo[0]);
    }
    if (blockIdx.x == 0 && tid == 0) {
        out[BB] = -aux_acc[0] / (aux_acc[1] + 1e-8f);
    }
}

extern "C" void kernel_launch(void* const* d_in, const int* in_sizes, int n_in,
                              void* d_out, int out_size, void* d_ws, size_t ws_size,
                              hipStream_t stream) {
    (void)in_sizes; (void)n_in; (void)out_size; (void)ws_size;
    const float* dense    = (const float*)d_in[0];
    const int*   sparse   = (const int*)d_in[1];
    const int*   seq_in   = (const int*)d_in[2];
    const int*   neg_in   = (const int*)d_in[3];
    const int*   item_in  = (const int*)d_in[4];
    const int*   hist     = (const int*)d_in[5];
    const float* emb_item = (const float*)d_in[6];
    const float* emb_neg  = (const float*)d_in[7];
    const float* emb_oth  = (const float*)d_in[8];
    const float* g1Wx = (const float*)d_in[9];
    const float* g1Wh = (const float*)d_in[10];
    const float* g1b  = (const float*)d_in[11];
    const float* aW1  = (const float*)d_in[12];
    const float* ab1  = (const float*)d_in[13];
    const float* aW2  = (const float*)d_in[14];
    const float* ab2  = (const float*)d_in[15];
    const float* aW3  = (const float*)d_in[16];
    const float* ab3  = (const float*)d_in[17];
    const float* g2Wx = (const float*)d_in[18];
    const float* g2Wh = (const float*)d_in[19];
    const float* g2b  = (const float*)d_in[20];
    const float* bng  = (const float*)d_in[21];
    const float* bnb  = (const float*)d_in[22];
    const float* W0   = (const float*)d_in[23];
    const float* b0f  = (const float*)d_in[24];
    const float* a0f  = (const float*)d_in[25];
    const float* W1f  = (const float*)d_in[26];
    const float* b1f  = (const float*)d_in[27];
    const float* a1f  = (const float*)d_in[28];
    const float* W2f  = (const float*)d_in[29];
    const float* b2f  = (const float*)d_in[30];
    const float* a2f  = (const float*)d_in[31];
    const float* Wo   = (const float*)d_in[32];
    const float* bo   = (const float*)d_in[33];

    float* ws          = (float*)d_ws;
    float* seq_h       = ws;                      // B*T*64 = 13,107,200 floats
    float* scoresW     = seq_h + 13107200;        // B*T = 204800
    float* target      = scoresW + 204800;        // B*64
    float* qproj       = target + 131072;         // B*64
    float* final_state = qproj + 131072;          // B*64
    float* Wq          = final_state + 131072;    // 4096
    float* Wk          = Wq + 4096;
    float* Wp          = Wk + 4096;
    short* WxB1        = (short*)(Wp + 4096);     // 12288 shorts each (6144 floats)
    short* WhB1        = WxB1 + 12288;
    short* WxB2        = WhB1 + 12288;
    short* WhB2        = WxB2 + 12288;
    float* aux_acc     = (float*)(WhB2 + 12288);  // 2 floats (total ~54.9 MB)

    k_prep<<<16, 256, 0, stream>>>(aW1, Wq, Wk, Wp, aux_acc);
    k_prepW<<<dim3(48, 4), 256, 0, stream>>>(g1Wx, g1Wh, g2Wx, g2Wh, WxB1, WhB1, WxB2, WhB2);
    k_target<<<BB, 64, 0, stream>>>(item_in, emb_item, Wq, ab1, target, qproj);
    k_scan<0><<<256, 256, 0, stream>>>(seq_in, emb_item, WxB1, WhB1, g1b, hist, nullptr, seq_h, nullptr);
    k_attn<<<BB, 256, 0, stream>>>(seq_h, target, qproj, seq_in, aW2, ab2, aW3, ab3, Wk, Wp, scoresW);
    k_scan<1><<<256, 256, 0, stream>>>(seq_in, seq_h, WxB2, WhB2, g2b, hist, scoresW, nullptr, final_state);
    k_aux<<<BB, 64, 0, stream>>>(seq_h, seq_in, neg_in, emb_item, emb_neg, aux_acc);
    k_mlp<<<256, 256, 0, stream>>>(final_state, target, dense, sparse, emb_oth, bng, bnb,
                                   W0, b0f, a0f, W1f, b1f, a1f, W2f, b2f, a2f, Wo, bo,
                                   aux_acc, (float*)d_out);
}

// Round 4
// 598.389 us; speedup vs baseline: 3.1979x; 1.4787x over previous
//
#include <hip/hip_runtime.h>
#include <math.h>

// DIEN: B=2048 T=100 D=64.
// Round 4: MFMA attention (bf16 GEMM, wave-parallel softmax). Scans/aux/mlp unchanged.

#define DEV __device__ __forceinline__

constexpr int BB = 2048;
constexpr int TT = 100;

typedef __attribute__((ext_vector_type(8))) short bf16x8;
typedef __attribute__((ext_vector_type(4))) float f32x4;

#define MFMA16(a, b, c) __builtin_amdgcn_mfma_f32_16x16x32_bf16(a, b, c, 0, 0, 0)

DEV float sigmoidf_(float x) { return 1.0f / (1.0f + __expf(-x)); }
DEV float tanhf_(float x)    { return 1.0f - 2.0f / (__expf(2.0f * x) + 1.0f); }
DEV short f2bf(float f) {  // fp32 -> bf16 bits, round-to-nearest-even
    unsigned u = __float_as_uint(f);
    u = (u + 0x7FFFu + ((u >> 16) & 1u)) >> 16;
    return (short)u;
}
DEV float bf2f(short s) { return __uint_as_float(((unsigned)(unsigned short)s) << 16); }

// ---------------- prep: fold att_W1 into Wq/Wk/Wp; zero aux accumulator ----------------
__global__ void k_prep(const float* __restrict__ W1, float* Wq, float* Wk, float* Wp, float* aux_acc) {
    int i = blockIdx.x * 256 + threadIdx.x;  // 16 blocks x 256 = 4096
    if (i < 4096) {
        int k = i >> 6, c = i & 63;
        float a  = W1[k * 64 + c];
        float bb = W1[(64 + k) * 64 + c];
        float cc = W1[(128 + k) * 64 + c];
        float dd = W1[(192 + k) * 64 + c];
        Wq[i] = a + cc;   // qe @ (W1a + W1c)
        Wk[i] = bb - cc;  // keys @ (W1b - W1c)
        Wp[i] = dd;       // (qe*keys) @ W1d
    }
    if (blockIdx.x == 0 && threadIdx.x == 0) { aux_acc[0] = 0.0f; aux_acc[1] = 0.0f; }
}

// ---------------- prepW: pack GRU weights (64x192 fp32) into bf16 MFMA B-fragments ----
__global__ __launch_bounds__(256)
void k_prepW(const float* __restrict__ Wa, const float* __restrict__ Wb,
             const float* __restrict__ Wc, const float* __restrict__ Wd,
             short* __restrict__ oa, short* __restrict__ ob,
             short* __restrict__ oc, short* __restrict__ od) {
    const float* W; short* o;
    switch (blockIdx.y) {
        case 0:  W = Wa; o = oa; break;
        case 1:  W = Wb; o = ob; break;
        case 2:  W = Wc; o = oc; break;
        default: W = Wd; o = od; break;
    }
    int d = blockIdx.x * 256 + threadIdx.x;  // 48 blocks -> 12288
    int frag = d >> 9, l = (d >> 3) & 63, i = d & 7;
    int n = frag >> 1, kt = frag & 1;
    int k = kt * 32 + ((l >> 4) << 3) + i;
    int c = (n << 4) + (l & 15);
    o[d] = f2bf(W[k * 192 + c]);
}

// ---------------- prepA: pack Wk/Wp (64x64 fp32) into bf16 B-frags (f = kt*4+n) -------
__global__ __launch_bounds__(256)
void k_prepA(const float* __restrict__ Wk, const float* __restrict__ Wp,
             short* __restrict__ oK, short* __restrict__ oP) {
    int d = blockIdx.x * 256 + threadIdx.x;  // 32 blocks -> 8192 (2 mats x 4096)
    int mat = d >> 12, i = d & 4095;
    int f = i >> 9, l = (i >> 3) & 63, e = i & 7;
    int kt = f >> 2, n = f & 3;
    int k = kt * 32 + ((l >> 4) << 3) + e;
    int c = (n << 4) + (l & 15);
    if (mat == 0) oK[i] = f2bf(Wk[k * 64 + c]);
    else          oP[i] = f2bf(Wp[k * 64 + c]);
}

// ---------------- target gather + qproj = q@Wq + b1 ----------------
__global__ __launch_bounds__(64)
void k_target(const int* __restrict__ item, const float* __restrict__ emb_item,
              const float* __restrict__ Wq, const float* __restrict__ b1,
              float* target, float* qproj) {
    int b = blockIdx.x, c = threadIdx.x;
    __shared__ float q[64];
    int idx = item[b];
    float tv = emb_item[(size_t)idx * 64 + c];
    target[b * 64 + c] = tv;
    q[c] = tv;
    __syncthreads();
    float acc = b1[c];
#pragma unroll
    for (int k = 0; k < 64; ++k) acc = fmaf(q[k], Wq[k * 64 + c], acc);
    qproj[b * 64 + c] = acc;
}

// ---------------- MFMA GRU / AUGRU scan (unchanged from round 3) ----------------------
template <int MODE>
__global__ __launch_bounds__(256, 1)
void k_scan(const int* __restrict__ seq_idx, const float* __restrict__ src,
            const short* __restrict__ WxB, const short* __restrict__ WhB,
            const float* __restrict__ bias, const int* __restrict__ hist_len,
            const float* __restrict__ scores,
            float* __restrict__ seq_out, float* __restrict__ final_out) {
    __shared__ short hA[2][1024];

    const int tid  = threadIdx.x;
    const int w    = tid >> 6;
    const int lane = tid & 63;
    const int lr   = lane & 15;
    const int kg   = lane >> 4;
    const int b0   = blockIdx.x * 8;

    for (int i = tid; i < 2048; i += 256) ((short*)hA)[i] = 0;

    bf16x8 bx[3][2], bh[3][2];
#pragma unroll
    for (int n3 = 0; n3 < 3; ++n3) {
        int n = w + n3 * 4;
#pragma unroll
        for (int kt = 0; kt < 2; ++kt) {
            bx[n3][kt] = *(const bf16x8*)(WxB + (((n * 2 + kt) * 64 + lane) << 3));
            bh[n3][kt] = *(const bf16x8*)(WhB + (((n * 2 + kt) * 64 + lane) << 3));
        }
    }

    const int   c0  = (w << 4) + lr;
    const float bz  = bias[c0];
    const float brr = bias[64 + c0];
    const float bhb = bias[128 + c0];
    const int   qc  = kg & 1;
    const bool  act = (kg < 2);

    int   hist[4];
    float h[4] = {0.f, 0.f, 0.f, 0.f};
#pragma unroll
    for (int j = 0; j < 4; ++j) hist[j] = hist_len[b0 + qc * 4 + j];

    const int rload = (lr < 8) ? lr : 7;
    float4 ec[4], en[4];
    float  scc[4] = {1.f, 1.f, 1.f, 1.f}, scn[4];

    {
        const float* eb;
        if (MODE == 0) { int idx = seq_idx[(b0 + rload) * TT]; eb = src + (size_t)idx * 64; }
        else           { eb = src + ((size_t)(b0 + rload) * TT) * 64; }
        ec[0] = *(const float4*)(eb + kg * 8);
        ec[1] = *(const float4*)(eb + kg * 8 + 4);
        ec[2] = *(const float4*)(eb + 32 + kg * 8);
        ec[3] = *(const float4*)(eb + 32 + kg * 8 + 4);
        if (MODE == 1) {
#pragma unroll
            for (int j = 0; j < 4; ++j) scc[j] = scores[(b0 + qc * 4 + j) * TT];
        }
    }
    __syncthreads();

    for (int t = 0; t < TT; ++t) {
        const int buf = t & 1;
        const int so0 = lr * 64 + (((kg    ) ^ (lr & 7)) << 3);
        const int so1 = lr * 64 + (((4 + kg) ^ (lr & 7)) << 3);
        bf16x8 ha0 = *(const bf16x8*)&hA[buf][so0];
        bf16x8 ha1 = *(const bf16x8*)&hA[buf][so1];

        if (t < TT - 1) {
            const float* eb;
            if (MODE == 0) { int idx = seq_idx[(b0 + rload) * TT + t + 1]; eb = src + (size_t)idx * 64; }
            else           { eb = src + ((size_t)(b0 + rload) * TT + (t + 1)) * 64; }
            en[0] = *(const float4*)(eb + kg * 8);
            en[1] = *(const float4*)(eb + kg * 8 + 4);
            en[2] = *(const float4*)(eb + 32 + kg * 8);
            en[3] = *(const float4*)(eb + 32 + kg * 8 + 4);
            if (MODE == 1) {
#pragma unroll
                for (int j = 0; j < 4; ++j) scn[j] = scores[(b0 + qc * 4 + j) * TT + t + 1];
            }
        }

        bf16x8 ea0, ea1;
        ea0[0] = f2bf(ec[0].x); ea0[1] = f2bf(ec[0].y); ea0[2] = f2bf(ec[0].z); ea0[3] = f2bf(ec[0].w);
        ea0[4] = f2bf(ec[1].x); ea0[5] = f2bf(ec[1].y); ea0[6] = f2bf(ec[1].z); ea0[7] = f2bf(ec[1].w);
        ea1[0] = f2bf(ec[2].x); ea1[1] = f2bf(ec[2].y); ea1[2] = f2bf(ec[2].z); ea1[3] = f2bf(ec[2].w);
        ea1[4] = f2bf(ec[3].x); ea1[5] = f2bf(ec[3].y); ea1[6] = f2bf(ec[3].z); ea1[7] = f2bf(ec[3].w);

        f32x4 az  = {0.f, 0.f, 0.f, 0.f};
        f32x4 ar  = {0.f, 0.f, 0.f, 0.f};
        f32x4 ahx = {0.f, 0.f, 0.f, 0.f};
        f32x4 ahh = {0.f, 0.f, 0.f, 0.f};
        az  = MFMA16(ea0, bx[0][0], az);  az  = MFMA16(ea1, bx[0][1], az);
        az  = MFMA16(ha0, bh[0][0], az);  az  = MFMA16(ha1, bh[0][1], az);
        ar  = MFMA16(ea0, bx[1][0], ar);  ar  = MFMA16(ea1, bx[1][1], ar);
        ar  = MFMA16(ha0, bh[1][0], ar);  ar  = MFMA16(ha1, bh[1][1], ar);
        ahx = MFMA16(ea0, bx[2][0], ahx); ahx = MFMA16(ea1, bx[2][1], ahx);
        ahh = MFMA16(ha0, bh[2][0], ahh); ahh = MFMA16(ha1, bh[2][1], ahh);

        if (act) {
#pragma unroll
            for (int j = 0; j < 4; ++j) {
                float a01  = (MODE == 1) ? scc[j] : 1.0f;
                float z    = sigmoidf_(az[j] + bz) * a01;
                float r    = sigmoidf_(ar[j] + brr);
                float cand = tanhf_(ahx[j] + bhb + r * ahh[j]);
                float hn   = h[j] + z * (cand - h[j]);
                h[j] = (t < hist[j]) ? hn : h[j];
                int rr = qc * 4 + j;
                int sw = rr * 64 + ((((c0 >> 3)) ^ (rr & 7)) << 3) + (c0 & 7);
                hA[buf ^ 1][sw] = f2bf(h[j]);
                if (MODE == 0)
                    seq_out[((size_t)(b0 + rr) * TT + t) * 64 + c0] = h[j];
            }
        }
        if (t < TT - 1) {
#pragma unroll
            for (int q4 = 0; q4 < 4; ++q4) ec[q4] = en[q4];
            if (MODE == 1) {
#pragma unroll
                for (int j = 0; j < 4; ++j) scc[j] = scn[j];
            }
        }
        __syncthreads();
    }

    if (MODE == 1 && act) {
#pragma unroll
        for (int j = 0; j < 4; ++j) {
            int rr = qc * 4 + j;
            final_out[(b0 + rr) * 64 + c0] = h[j];
        }
    }
}

// ---------------- MFMA attention: one block per b ----------------
// Phase A: h1 = sigmoid([keys|pk] @ [Wk;Wp] + qproj) via 16 MFMA per 16-row tile.
// Phase B: logits via paired threads (8 cols each + shfl combine).
// Softmax: wave-parallel shuffle reduce. 4 barriers total.
__global__ __launch_bounds__(256)
void k_attn(const float* __restrict__ seq_h, const float* __restrict__ target,
            const float* __restrict__ qproj, const int* __restrict__ seq_idx,
            const short* __restrict__ WkB, const short* __restrict__ WpB,
            const float* __restrict__ W2g, const float* __restrict__ b2g,
            const float* __restrict__ W3g, const float* __restrict__ b3g,
            float* __restrict__ scores) {
    __shared__ __align__(16) short keysb[7168];  // 112 rows x 64 cols bf16, XOR-swizzled
    __shared__ __align__(16) short pkb[7168];    // pk; h1 overwrites row-disjoint in phase A
    __shared__ float W2_s[1024];
    __shared__ float q_s[64], qp_s[64];
    __shared__ float b2_s[16], W3_s[16];
    __shared__ float lg[112];

    const int b = blockIdx.x, tid = threadIdx.x;
    const int w = tid >> 6, lane = tid & 63;

    // B fragments (Wk, Wp) in registers
    bf16x8 BK[2][4], BP[2][4];
#pragma unroll
    for (int kt = 0; kt < 2; ++kt)
#pragma unroll
        for (int n = 0; n < 4; ++n) {
            BK[kt][n] = *(const bf16x8*)(WkB + (((kt * 4 + n) * 64 + lane) << 3));
            BP[kt][n] = *(const bf16x8*)(WpB + (((kt * 4 + n) * 64 + lane) << 3));
        }
    if (tid < 64)  { q_s[tid] = target[b * 64 + tid]; qp_s[tid] = qproj[b * 64 + tid]; }
    if (tid >= 64 && tid < 80) { b2_s[tid - 64] = b2g[tid - 64]; W3_s[tid - 64] = W3g[tid - 64]; }
    for (int i = tid; i < 1024; i += 256) W2_s[i] = W2g[i];
    __syncthreads();

    // stage keys + pk (fp32 -> bf16, swizzle: byte ^= (row&7)<<4 on bits 4-6)
    for (int i4 = tid; i4 < 1792; i4 += 256) {   // 7168/4 groups of 4 cols
        int r = i4 >> 4, c4 = i4 & 15;
        short4 kv, pv;
        if (r < TT) {
            float4 f = *(const float4*)(seq_h + (size_t)b * (TT * 64) + r * 64 + c4 * 4);
            float q0 = q_s[c4 * 4], q1 = q_s[c4 * 4 + 1], q2 = q_s[c4 * 4 + 2], q3 = q_s[c4 * 4 + 3];
            kv = make_short4(f2bf(f.x), f2bf(f.y), f2bf(f.z), f2bf(f.w));
            pv = make_short4(f2bf(f.x * q0), f2bf(f.y * q1), f2bf(f.z * q2), f2bf(f.w * q3));
        } else {
            kv = make_short4(0, 0, 0, 0); pv = kv;
        }
        int off = r * 128 + ((c4 * 8) ^ ((r & 7) << 4));
        *(short4*)((char*)keysb + off) = kv;
        *(short4*)((char*)pkb + off)   = pv;
    }
    __syncthreads();

    // Phase A: 7 row-tiles of 16; wave w does rt = w, w+4
    for (int rt = w; rt < 7; rt += 4) {
        const int r0 = rt * 16;
        const int arow = r0 + (lane & 15);
        const int kb = lane >> 4;
        bf16x8 AK[2], AP[2];
#pragma unroll
        for (int kt = 0; kt < 2; ++kt) {
            int off = arow * 128 + (((kt * 64) + kb * 16) ^ ((arow & 7) << 4));
            AK[kt] = *(const bf16x8*)((const char*)keysb + off);
            AP[kt] = *(const bf16x8*)((const char*)pkb + off);
        }
        f32x4 C[4];
#pragma unroll
        for (int n = 0; n < 4; ++n) { C[n] = (f32x4){0.f, 0.f, 0.f, 0.f}; }
#pragma unroll
        for (int n = 0; n < 4; ++n) {
            C[n] = MFMA16(AK[0], BK[0][n], C[n]);
            C[n] = MFMA16(AK[1], BK[1][n], C[n]);
            C[n] = MFMA16(AP[0], BP[0][n], C[n]);
            C[n] = MFMA16(AP[1], BP[1][n], C[n]);
        }
        // epilogue: h1 = sigmoid(C + qproj), bf16 into pkb (h1 buffer)
#pragma unroll
        for (int n = 0; n < 4; ++n) {
            int col = n * 16 + (lane & 15);
            float qp = qp_s[col];
#pragma unroll
            for (int j = 0; j < 4; ++j) {
                int row = r0 + (lane >> 4) * 4 + j;
                float h1 = sigmoidf_(C[n][j] + qp);
                int off = row * 128 + ((col * 2) ^ ((row & 7) << 4));
                *(short*)((char*)pkb + off) = f2bf(h1);
            }
        }
    }
    __syncthreads();

    // Phase B: logits. Pair (tid, tid^1) shares row t = tid>>1; each does 8 of 16 h2 cols.
    {
        int t = tid >> 1, half = tid & 1;
        if (t < TT) {
            int j0 = half * 8;
            float acc[8];
#pragma unroll
            for (int jj = 0; jj < 8; ++jj) acc[jj] = b2_s[j0 + jj];
#pragma unroll
            for (int ch = 0; ch < 8; ++ch) {
                int off = t * 128 + ((ch * 16) ^ ((t & 7) << 4));
                bf16x8 hv = *(const bf16x8*)((const char*)pkb + off);
#pragma unroll
                for (int e = 0; e < 8; ++e) {
                    float hf = bf2f(hv[e]);
                    int k = ch * 8 + e;
#pragma unroll
                    for (int jj = 0; jj < 8; ++jj)
                        acc[jj] = fmaf(hf, W2_s[k * 16 + j0 + jj], acc[jj]);
                }
            }
            float part = 0.f;
#pragma unroll
            for (int jj = 0; jj < 8; ++jj) part += sigmoidf_(acc[jj]) * W3_s[j0 + jj];
            part += __shfl_xor(part, 1);
            if (half == 0) {
                bool m = (seq_idx[b * TT + t] != 0);
                lg[t] = m ? (part + b3g[0]) : -1e9f;
            }
        }
    }
    __syncthreads();

    // softmax over t=0..99 (wave 0), then write scores
    if (w == 0) {
        float a  = lg[lane];
        float bv = (lane + 64 < TT) ? lg[lane + 64] : -1e30f;
        float mx = fmaxf(a, bv);
#pragma unroll
        for (int s = 32; s; s >>= 1) mx = fmaxf(mx, __shfl_xor(mx, s));
        float ea = __expf(a - mx);
        float eb = (lane + 64 < TT) ? __expf(bv - mx) : 0.f;
        float sum = ea + eb;
#pragma unroll
        for (int s = 32; s; s >>= 1) sum += __shfl_xor(sum, s);
        float inv = 1.0f / sum;
        scores[b * TT + lane] = ea * inv;
        if (lane + 64 < TT) scores[b * TT + lane + 64] = eb * inv;
    }
}

// ---------------- aux loss: one wave per batch row ----------------
__global__ __launch_bounds__(64)
void k_aux(const float* __restrict__ seq_h, const int* __restrict__ seq_idx,
           const int* __restrict__ neg_idx, const float* __restrict__ emb_item,
           const float* __restrict__ emb_neg, float* aux_acc) {
    int b = blockIdx.x, l = threadIdx.x;
    float num = 0.0f;
    float den = 0.0f;
    for (int t = 0; t < TT - 1; ++t) {
        int ip = seq_idx[b * TT + t + 1];
        int in_ = neg_idx[b * TT + t + 1];
        float h = seq_h[(size_t)b * (TT * 64) + t * 64 + l];
        float dp = h * emb_item[(size_t)ip * 64 + l];
        float dn = h * emb_neg[(size_t)in_ * 64 + l];
#pragma unroll
        for (int s = 32; s; s >>= 1) { dp += __shfl_xor(dp, s); dn += __shfl_xor(dn, s); }
        if (l == 0 && ip != 0) {
            float pp = sigmoidf_(dp), pn = sigmoidf_(dn);
            num += __logf(pp + 1e-8f) + __logf(1.0f - pn + 1e-8f);
            den += 1.0f;
        }
    }
    if (l == 0) {
        atomicAdd(&aux_acc[0], num);
        atomicAdd(&aux_acc[1], den);
    }
}

// ---------------- final MLP (BN + 3x dice FFN + sigmoid head) + aux write ----------------
__global__ __launch_bounds__(256)
void k_mlp(const float* __restrict__ final_state, const float* __restrict__ target,
           const float* __restrict__ dense, const int* __restrict__ sparse,
           const float* __restrict__ emb_other,
           const float* __restrict__ bng, const float* __restrict__ bnb,
           const float* __restrict__ W0, const float* __restrict__ bb0, const float* __restrict__ al0,
           const float* __restrict__ W1, const float* __restrict__ bb1, const float* __restrict__ al1,
           const float* __restrict__ W2, const float* __restrict__ bb2, const float* __restrict__ al2,
           const float* __restrict__ Wo, const float* __restrict__ bo,
           const float* __restrict__ aux_acc, float* __restrict__ out) {
    const float inv1 = 0.9995003747f;  // 1/sqrt(1+BN_EPS)
    int tid = threadIdx.x, b0 = blockIdx.x * 8;
    __shared__ float x_s[8][200], h1_s[8][256], h2_s[8][128], h3_s[8][64];

    for (int i = tid; i < 8 * 200; i += 256) {
        int r = i / 200, cc = i - r * 200, b = b0 + r;
        float v;
        if (cc < 64)       v = final_state[b * 64 + cc];
        else if (cc < 128) v = target[b * 64 + cc - 64];
        else if (cc < 136) v = dense[b * 8 + cc - 128];
        else if (cc < 168) v = emb_other[(size_t)sparse[b * 2 + 0] * 32 + (cc - 136)];
        else               v = emb_other[(size_t)10000 * 32 + (size_t)sparse[b * 2 + 1] * 32 + (cc - 168)];
        x_s[r][cc] = fmaf(bng[cc] * inv1, v, bnb[cc]);
    }
    __syncthreads();
    {   // L1: 200 -> 256, dice
        int r = tid >> 5, cb = tid & 31;
        float acc[8];
#pragma unroll
        for (int j = 0; j < 8; ++j) acc[j] = bb0[cb + 32 * j];
        for (int k = 0; k < 200; ++k) {
            float xv = x_s[r][k];
#pragma unroll
            for (int j = 0; j < 8; ++j) acc[j] = fmaf(xv, W0[k * 256 + cb + 32 * j], acc[j]);
        }
#pragma unroll
        for (int j = 0; j < 8; ++j) {
            float y = acc[j];
            float p = sigmoidf_(y * inv1);
            h1_s[r][cb + 32 * j] = y * (p + (1.0f - p) * al0[cb + 32 * j]);
        }
    }
    __syncthreads();
    {   // L2: 256 -> 128, dice
        int r = tid >> 5, cb = tid & 31;
        float acc[4];
#pragma unroll
        for (int j = 0; j < 4; ++j) acc[j] = bb1[cb + 32 * j];
        for (int k = 0; k < 256; ++k) {
            float xv = h1_s[r][k];
#pragma unroll
            for (int j = 0; j < 4; ++j) acc[j] = fmaf(xv, W1[k * 128 + cb + 32 * j], acc[j]);
        }
#pragma unroll
        for (int j = 0; j < 4; ++j) {
            float y = acc[j];
            float p = sigmoidf_(y * inv1);
            h2_s[r][cb + 32 * j] = y * (p + (1.0f - p) * al1[cb + 32 * j]);
        }
    }
    __syncthreads();
    {   // L3: 128 -> 64, dice
        int r = tid >> 5, cb = tid & 31;
        float acc[2] = {bb2[cb], bb2[cb + 32]};
        for (int k = 0; k < 128; ++k) {
            float xv = h2_s[r][k];
            acc[0] = fmaf(xv, W2[k * 64 + cb], acc[0]);
            acc[1] = fmaf(xv, W2[k * 64 + cb + 32], acc[1]);
        }
#pragma unroll
        for (int j = 0; j < 2; ++j) {
            float y = acc[j];
            float p = sigmoidf_(y * inv1);
            h3_s[r][cb + 32 * j] = y * (p + (1.0f - p) * al2[cb + 32 * j]);
        }
    }
    __syncthreads();
    {   // head: 64 -> 1 sigmoid
        int r = tid >> 5, l = tid & 31;
        float v = h3_s[r][l] * Wo[l] + h3_s[r][l + 32] * Wo[l + 32];
#pragma unroll
        for (int s = 16; s; s >>= 1) v += __shfl_xor(v, s, 32);
        if (l == 0) out[b0 + r] = sigmoidf_(v + bo[0]);
    }
    if (blockIdx.x == 0 && tid == 0) {
        out[BB] = -aux_acc[0] / (aux_acc[1] + 1e-8f);
    }
}

extern "C" void kernel_launch(void* const* d_in, const int* in_sizes, int n_in,
                              void* d_out, int out_size, void* d_ws, size_t ws_size,
                              hipStream_t stream) {
    (void)in_sizes; (void)n_in; (void)out_size; (void)ws_size;
    const float* dense    = (const float*)d_in[0];
    const int*   sparse   = (const int*)d_in[1];
    const int*   seq_in   = (const int*)d_in[2];
    const int*   neg_in   = (const int*)d_in[3];
    const int*   item_in  = (const int*)d_in[4];
    const int*   hist     = (const int*)d_in[5];
    const float* emb_item = (const float*)d_in[6];
    const float* emb_neg  = (const float*)d_in[7];
    const float* emb_oth  = (const float*)d_in[8];
    const float* g1Wx = (const float*)d_in[9];
    const float* g1Wh = (const float*)d_in[10];
    const float* g1b  = (const float*)d_in[11];
    const float* aW1  = (const float*)d_in[12];
    const float* ab1  = (const float*)d_in[13];
    const float* aW2  = (const float*)d_in[14];
    const float* ab2  = (const float*)d_in[15];
    const float* aW3  = (const float*)d_in[16];
    const float* ab3  = (const float*)d_in[17];
    const float* g2Wx = (const float*)d_in[18];
    const float* g2Wh = (const float*)d_in[19];
    const float* g2b  = (const float*)d_in[20];
    const float* bng  = (const float*)d_in[21];
    const float* bnb  = (const float*)d_in[22];
    const float* W0   = (const float*)d_in[23];
    const float* b0f  = (const float*)d_in[24];
    const float* a0f  = (const float*)d_in[25];
    const float* W1f  = (const float*)d_in[26];
    const float* b1f  = (const float*)d_in[27];
    const float* a1f  = (const float*)d_in[28];
    const float* W2f  = (const float*)d_in[29];
    const float* b2f  = (const float*)d_in[30];
    const float* a2f  = (const float*)d_in[31];
    const float* Wo   = (const float*)d_in[32];
    const float* bo   = (const float*)d_in[33];

    float* ws          = (float*)d_ws;
    float* seq_h       = ws;                      // B*T*64 = 13,107,200 floats
    float* scoresW     = seq_h + 13107200;        // B*T = 204800
    float* target      = scoresW + 204800;        // B*64
    float* qproj       = target + 131072;         // B*64
    float* final_state = qproj + 131072;          // B*64
    float* Wq          = final_state + 131072;    // 4096
    float* Wk          = Wq + 4096;
    float* Wp          = Wk + 4096;
    short* WxB1        = (short*)(Wp + 4096);     // 12288 shorts each
    short* WhB1        = WxB1 + 12288;
    short* WxB2        = WhB1 + 12288;
    short* WhB2        = WxB2 + 12288;
    short* WkB         = WhB2 + 12288;            // 4096 shorts
    short* WpB         = WkB + 4096;              // 4096 shorts
    float* aux_acc     = (float*)(WpB + 4096);    // 2 floats

    k_prep<<<16, 256, 0, stream>>>(aW1, Wq, Wk, Wp, aux_acc);
    k_prepW<<<dim3(48, 4), 256, 0, stream>>>(g1Wx, g1Wh, g2Wx, g2Wh, WxB1, WhB1, WxB2, WhB2);
    k_prepA<<<32, 256, 0, stream>>>(Wk, Wp, WkB, WpB);
    k_target<<<BB, 64, 0, stream>>>(item_in, emb_item, Wq, ab1, target, qproj);
    k_scan<0><<<256, 256, 0, stream>>>(seq_in, emb_item, WxB1, WhB1, g1b, hist, nullptr, seq_h, nullptr);
    k_attn<<<BB, 256, 0, stream>>>(seq_h, target, qproj, seq_in, WkB, WpB, aW2, ab2, aW3, ab3, scoresW);
    k_scan<1><<<256, 256, 0, stream>>>(seq_in, seq_h, WxB2, WhB2, g2b, hist, scoresW, nullptr, final_state);
    k_aux<<<BB, 64, 0, stream>>>(seq_h, seq_in, neg_in, emb_item, emb_neg, aux_acc);
    k_mlp<<<256, 256, 0, stream>>>(final_state, target, dense, sparse, emb_oth, bng, bnb,
                                   W0, b0f, a0f, W1f, b1f, a1f, W2f, b2f, a2f, Wo, bo,
                                   aux_acc, (float*)d_out);
}

// Round 5
// 598.170 us; speedup vs baseline: 3.1991x; 1.0004x over previous
//
#include <hip/hip_runtime.h>
#include <math.h>

// DIEN: B=2048 T=100 D=64.
// Round 5: light barriers + 4-row/2-block-per-CU scans, bf16 seq_h, parallel aux.

#define DEV __device__ __forceinline__

constexpr int BB = 2048;
constexpr int TT = 100;

typedef __attribute__((ext_vector_type(8))) short bf16x8;
typedef __attribute__((ext_vector_type(4))) float f32x4;

#define MFMA16(a, b, c) __builtin_amdgcn_mfma_f32_16x16x32_bf16(a, b, c, 0, 0, 0)

DEV float sigmoidf_(float x) { return 1.0f / (1.0f + __expf(-x)); }
DEV float tanhf_(float x)    { return 1.0f - 2.0f / (__expf(2.0f * x) + 1.0f); }
DEV short f2bf(float f) {  // fp32 -> bf16 bits, round-to-nearest-even
    unsigned u = __float_as_uint(f);
    u = (u + 0x7FFFu + ((u >> 16) & 1u)) >> 16;
    return (short)u;
}
DEV float bf2f(short s) { return __uint_as_float(((unsigned)(unsigned short)s) << 16); }

// LDS-only barrier: does NOT drain vmcnt (global stores/loads keep flying).
DEV void sync_lds() {
    __builtin_amdgcn_sched_barrier(0);
    asm volatile("s_waitcnt lgkmcnt(0)\n\ts_barrier" ::: "memory");
    __builtin_amdgcn_sched_barrier(0);
}

// ---------------- prep: fold att_W1 into Wq/Wk/Wp; zero aux accumulator ----------------
__global__ void k_prep(const float* __restrict__ W1, float* Wq, float* Wk, float* Wp, float* aux_acc) {
    int i = blockIdx.x * 256 + threadIdx.x;
    if (i < 4096) {
        int k = i >> 6, c = i & 63;
        float a  = W1[k * 64 + c];
        float bb = W1[(64 + k) * 64 + c];
        float cc = W1[(128 + k) * 64 + c];
        float dd = W1[(192 + k) * 64 + c];
        Wq[i] = a + cc;
        Wk[i] = bb - cc;
        Wp[i] = dd;
    }
    if (blockIdx.x == 0 && threadIdx.x == 0) { aux_acc[0] = 0.0f; aux_acc[1] = 0.0f; }
}

// ---------------- prepW: pack GRU weights (64x192 fp32) into bf16 MFMA B-fragments ----
__global__ __launch_bounds__(256)
void k_prepW(const float* __restrict__ Wa, const float* __restrict__ Wb,
             const float* __restrict__ Wc, const float* __restrict__ Wd,
             short* __restrict__ oa, short* __restrict__ ob,
             short* __restrict__ oc, short* __restrict__ od) {
    const float* W; short* o;
    switch (blockIdx.y) {
        case 0:  W = Wa; o = oa; break;
        case 1:  W = Wb; o = ob; break;
        case 2:  W = Wc; o = oc; break;
        default: W = Wd; o = od; break;
    }
    int d = blockIdx.x * 256 + threadIdx.x;  // 48 blocks -> 12288
    int frag = d >> 9, l = (d >> 3) & 63, i = d & 7;
    int n = frag >> 1, kt = frag & 1;
    int k = kt * 32 + ((l >> 4) << 3) + i;
    int c = (n << 4) + (l & 15);
    o[d] = f2bf(W[k * 192 + c]);
}

// ---------------- prepA: pack Wk/Wp (64x64 fp32) into bf16 B-frags (f = kt*4+n) -------
__global__ __launch_bounds__(256)
void k_prepA(const float* __restrict__ Wk, const float* __restrict__ Wp,
             short* __restrict__ oK, short* __restrict__ oP) {
    int d = blockIdx.x * 256 + threadIdx.x;  // 32 blocks -> 8192
    int mat = d >> 12, i = d & 4095;
    int f = i >> 9, l = (i >> 3) & 63, e = i & 7;
    int kt = f >> 2, n = f & 3;
    int k = kt * 32 + ((l >> 4) << 3) + e;
    int c = (n << 4) + (l & 15);
    if (mat == 0) oK[i] = f2bf(Wk[k * 64 + c]);
    else          oP[i] = f2bf(Wp[k * 64 + c]);
}

// ---------------- target gather + qproj = q@Wq + b1 ----------------
__global__ __launch_bounds__(64)
void k_target(const int* __restrict__ item, const float* __restrict__ emb_item,
              const float* __restrict__ Wq, const float* __restrict__ b1,
              float* target, float* qproj) {
    int b = blockIdx.x, c = threadIdx.x;
    __shared__ float q[64];
    int idx = item[b];
    float tv = emb_item[(size_t)idx * 64 + c];
    target[b * 64 + c] = tv;
    q[c] = tv;
    __syncthreads();
    float acc = b1[c];
#pragma unroll
    for (int k = 0; k < 64; ++k) acc = fmaf(q[k], Wq[k * 64 + c], acc);
    qproj[b * 64 + c] = acc;
}

// ---------------- MFMA GRU / AUGRU scan: 4 batch rows per block, 512 blocks -----------
// 2 blocks/CU co-resident (128-VGPR cap) => 2 waves/SIMD latency overlap.
// Per-step barrier is LDS-only (global stores never drain).
template <int MODE>  // 0 = GRU1 (gather fp32 emb, write bf16 seq_h), 1 = AUGRU (read bf16 seq_h)
__global__ __launch_bounds__(256, 2)
void k_scan(const int* __restrict__ seq_idx, const float* __restrict__ embf,
            const short* __restrict__ seqb,
            const short* __restrict__ WxB, const short* __restrict__ WhB,
            const float* __restrict__ bias, const int* __restrict__ hist_len,
            const float* __restrict__ scores,
            short* __restrict__ seq_out, float* __restrict__ final_out) {
    __shared__ short hA[2][1024];  // [buf][row*64 + swz], rows 4..15 stay zero

    const int tid  = threadIdx.x;
    const int w    = tid >> 6;
    const int lane = tid & 63;
    const int lr   = lane & 15;
    const int kg   = lane >> 4;
    const int b0   = blockIdx.x * 4;

    for (int i = tid; i < 2048; i += 256) ((short*)hA)[i] = 0;

    // B-fragments (weights) in registers for the whole scan
    bf16x8 bx[3][2], bh[3][2];
#pragma unroll
    for (int n3 = 0; n3 < 3; ++n3) {
        int n = w + n3 * 4;
#pragma unroll
        for (int kt = 0; kt < 2; ++kt) {
            bx[n3][kt] = *(const bf16x8*)(WxB + (((n * 2 + kt) * 64 + lane) << 3));
            bh[n3][kt] = *(const bf16x8*)(WhB + (((n * 2 + kt) * 64 + lane) << 3));
        }
    }

    const int   c0  = (w << 4) + lr;
    const float bz  = bias[c0];
    const float brr = bias[64 + c0];
    const float bhb = bias[128 + c0];
    const bool  act = (kg == 0);       // C rows 0..3 live here

    int   hist[4];
    float h[4] = {0.f, 0.f, 0.f, 0.f};
#pragma unroll
    for (int j = 0; j < 4; ++j) hist[j] = hist_len[b0 + j];

    const int rload = (lr < 4) ? lr : 3;   // rows 4..15 duplicate row 3 (dummy)
    bf16x8 ecb0, ecb1;
    float  scc[4] = {1.f, 1.f, 1.f, 1.f};

    {   // load e for t=0
        if (MODE == 0) {
            int idx = seq_idx[(b0 + rload) * TT];
            const float* eb = embf + (size_t)idx * 64;
            float4 f0 = *(const float4*)(eb + kg * 8);
            float4 f1 = *(const float4*)(eb + kg * 8 + 4);
            float4 f2 = *(const float4*)(eb + 32 + kg * 8);
            float4 f3 = *(const float4*)(eb + 32 + kg * 8 + 4);
            ecb0[0] = f2bf(f0.x); ecb0[1] = f2bf(f0.y); ecb0[2] = f2bf(f0.z); ecb0[3] = f2bf(f0.w);
            ecb0[4] = f2bf(f1.x); ecb0[5] = f2bf(f1.y); ecb0[6] = f2bf(f1.z); ecb0[7] = f2bf(f1.w);
            ecb1[0] = f2bf(f2.x); ecb1[1] = f2bf(f2.y); ecb1[2] = f2bf(f2.z); ecb1[3] = f2bf(f2.w);
            ecb1[4] = f2bf(f3.x); ecb1[5] = f2bf(f3.y); ecb1[6] = f2bf(f3.z); ecb1[7] = f2bf(f3.w);
        } else {
            const short* eb = seqb + ((size_t)(b0 + rload) * TT) * 64;
            ecb0 = *(const bf16x8*)(eb + kg * 8);
            ecb1 = *(const bf16x8*)(eb + 32 + kg * 8);
        }
        if (MODE == 1) {
#pragma unroll
            for (int j = 0; j < 4; ++j) scc[j] = scores[(b0 + j) * TT];
        }
    }
    __syncthreads();

    const int so0 = lr * 64 + (((kg    ) ^ (lr & 7)) << 3);
    const int so1 = lr * 64 + (((4 + kg) ^ (lr & 7)) << 3);

    for (int t = 0; t < TT; ++t) {
        const int buf = t & 1;
        bf16x8 ha0 = *(const bf16x8*)&hA[buf][so0];
        bf16x8 ha1 = *(const bf16x8*)&hA[buf][so1];

        // prefetch next step's e (and scores)
        float4 f0, f1, f2, f3;
        bf16x8 nb0, nb1;
        float scn[4];
        const bool haven = (t < TT - 1);
        if (haven) {
            if (MODE == 0) {
                int idx = seq_idx[(b0 + rload) * TT + t + 1];
                const float* eb = embf + (size_t)idx * 64;
                f0 = *(const float4*)(eb + kg * 8);
                f1 = *(const float4*)(eb + kg * 8 + 4);
                f2 = *(const float4*)(eb + 32 + kg * 8);
                f3 = *(const float4*)(eb + 32 + kg * 8 + 4);
            } else {
                const short* eb = seqb + ((size_t)(b0 + rload) * TT + (t + 1)) * 64;
                nb0 = *(const bf16x8*)(eb + kg * 8);
                nb1 = *(const bf16x8*)(eb + 32 + kg * 8);
#pragma unroll
                for (int j = 0; j < 4; ++j) scn[j] = scores[(b0 + j) * TT + t + 1];
            }
        }

        f32x4 az  = {0.f, 0.f, 0.f, 0.f};
        f32x4 ar  = {0.f, 0.f, 0.f, 0.f};
        f32x4 ahx = {0.f, 0.f, 0.f, 0.f};
        f32x4 ahh = {0.f, 0.f, 0.f, 0.f};
        az  = MFMA16(ecb0, bx[0][0], az);  az  = MFMA16(ecb1, bx[0][1], az);
        az  = MFMA16(ha0,  bh[0][0], az);  az  = MFMA16(ha1,  bh[0][1], az);
        ar  = MFMA16(ecb0, bx[1][0], ar);  ar  = MFMA16(ecb1, bx[1][1], ar);
        ar  = MFMA16(ha0,  bh[1][0], ar);  ar  = MFMA16(ha1,  bh[1][1], ar);
        ahx = MFMA16(ecb0, bx[2][0], ahx); ahx = MFMA16(ecb1, bx[2][1], ahx);
        ahh = MFMA16(ha0,  bh[2][0], ahh); ahh = MFMA16(ha1,  bh[2][1], ahh);

        if (act) {
#pragma unroll
            for (int j = 0; j < 4; ++j) {
                float a01  = (MODE == 1) ? scc[j] : 1.0f;
                float z    = sigmoidf_(az[j] + bz) * a01;
                float r    = sigmoidf_(ar[j] + brr);
                float cand = tanhf_(ahx[j] + bhb + r * ahh[j]);
                float hn   = h[j] + z * (cand - h[j]);
                h[j] = (t < hist[j]) ? hn : h[j];
                short v = f2bf(h[j]);
                int sw = j * 64 + (((c0 >> 3) ^ j) << 3) + (c0 & 7);  // rows 0..3: j&7==j
                hA[buf ^ 1][sw] = v;
                if (MODE == 0)
                    seq_out[((size_t)(b0 + j) * TT + t) * 64 + c0] = v;
            }
        }

        if (haven) {
            if (MODE == 0) {
                ecb0[0] = f2bf(f0.x); ecb0[1] = f2bf(f0.y); ecb0[2] = f2bf(f0.z); ecb0[3] = f2bf(f0.w);
                ecb0[4] = f2bf(f1.x); ecb0[5] = f2bf(f1.y); ecb0[6] = f2bf(f1.z); ecb0[7] = f2bf(f1.w);
                ecb1[0] = f2bf(f2.x); ecb1[1] = f2bf(f2.y); ecb1[2] = f2bf(f2.z); ecb1[3] = f2bf(f2.w);
                ecb1[4] = f2bf(f3.x); ecb1[5] = f2bf(f3.y); ecb1[6] = f2bf(f3.z); ecb1[7] = f2bf(f3.w);
            } else {
                ecb0 = nb0; ecb1 = nb1;
#pragma unroll
                for (int j = 0; j < 4; ++j) scc[j] = scn[j];
            }
        }
        sync_lds();
    }

    if (MODE == 1 && act) {
#pragma unroll
        for (int j = 0; j < 4; ++j)
            final_out[(b0 + j) * 64 + c0] = h[j];
    }
}

// ---------------- MFMA attention: one block per b (bf16 seq_h input) ----------------
__global__ __launch_bounds__(256)
void k_attn(const short* __restrict__ seq_h, const float* __restrict__ target,
            const float* __restrict__ qproj, const int* __restrict__ seq_idx,
            const short* __restrict__ WkB, const short* __restrict__ WpB,
            const float* __restrict__ W2g, const float* __restrict__ b2g,
            const float* __restrict__ W3g, const float* __restrict__ b3g,
            float* __restrict__ scores) {
    __shared__ __align__(16) short keysb[7168];  // 112 x 64 bf16, XOR-swizzled
    __shared__ __align__(16) short pkb[7168];    // pk; h1 overwrites in phase A
    __shared__ float W2_s[1024];
    __shared__ float q_s[64], qp_s[64];
    __shared__ float b2_s[16], W3_s[16];
    __shared__ float lg[112];

    const int b = blockIdx.x, tid = threadIdx.x;
    const int w = tid >> 6, lane = tid & 63;

    bf16x8 BK[2][4], BP[2][4];
#pragma unroll
    for (int kt = 0; kt < 2; ++kt)
#pragma unroll
        for (int n = 0; n < 4; ++n) {
            BK[kt][n] = *(const bf16x8*)(WkB + (((kt * 4 + n) * 64 + lane) << 3));
            BP[kt][n] = *(const bf16x8*)(WpB + (((kt * 4 + n) * 64 + lane) << 3));
        }
    if (tid < 64)  { q_s[tid] = target[b * 64 + tid]; qp_s[tid] = qproj[b * 64 + tid]; }
    if (tid >= 64 && tid < 80) { b2_s[tid - 64] = b2g[tid - 64]; W3_s[tid - 64] = W3g[tid - 64]; }
    for (int i = tid; i < 1024; i += 256) W2_s[i] = W2g[i];
    __syncthreads();

    // stage keys + pk (bf16 source)
    for (int i4 = tid; i4 < 1792; i4 += 256) {
        int r = i4 >> 4, c4 = i4 & 15;
        short4 kv, pv;
        if (r < TT) {
            short4 sv = *(const short4*)(seq_h + (size_t)b * (TT * 64) + r * 64 + c4 * 4);
            float q0 = q_s[c4 * 4], q1 = q_s[c4 * 4 + 1], q2 = q_s[c4 * 4 + 2], q3 = q_s[c4 * 4 + 3];
            kv = sv;
            pv = make_short4(f2bf(bf2f(sv.x) * q0), f2bf(bf2f(sv.y) * q1),
                             f2bf(bf2f(sv.z) * q2), f2bf(bf2f(sv.w) * q3));
        } else {
            kv = make_short4(0, 0, 0, 0); pv = kv;
        }
        int off = r * 128 + ((c4 * 8) ^ ((r & 7) << 4));
        *(short4*)((char*)keysb + off) = kv;
        *(short4*)((char*)pkb + off)   = pv;
    }
    __syncthreads();

    // Phase A: 7 row-tiles of 16; wave w does rt = w, w+4
    for (int rt = w; rt < 7; rt += 4) {
        const int r0 = rt * 16;
        const int arow = r0 + (lane & 15);
        const int kb = lane >> 4;
        bf16x8 AK[2], AP[2];
#pragma unroll
        for (int kt = 0; kt < 2; ++kt) {
            int off = arow * 128 + (((kt * 64) + kb * 16) ^ ((arow & 7) << 4));
            AK[kt] = *(const bf16x8*)((const char*)keysb + off);
            AP[kt] = *(const bf16x8*)((const char*)pkb + off);
        }
        f32x4 C[4];
#pragma unroll
        for (int n = 0; n < 4; ++n) { C[n] = (f32x4){0.f, 0.f, 0.f, 0.f}; }
#pragma unroll
        for (int n = 0; n < 4; ++n) {
            C[n] = MFMA16(AK[0], BK[0][n], C[n]);
            C[n] = MFMA16(AK[1], BK[1][n], C[n]);
            C[n] = MFMA16(AP[0], BP[0][n], C[n]);
            C[n] = MFMA16(AP[1], BP[1][n], C[n]);
        }
#pragma unroll
        for (int n = 0; n < 4; ++n) {
            int col = n * 16 + (lane & 15);
            float qp = qp_s[col];
#pragma unroll
            for (int j = 0; j < 4; ++j) {
                int row = r0 + (lane >> 4) * 4 + j;
                float h1 = sigmoidf_(C[n][j] + qp);
                int off = row * 128 + ((col * 2) ^ ((row & 7) << 4));
                *(short*)((char*)pkb + off) = f2bf(h1);
            }
        }
    }
    __syncthreads();

    // Phase B: logits. Pair (tid, tid^1) shares row t = tid>>1.
    {
        int t = tid >> 1, half = tid & 1;
        if (t < TT) {
            int j0 = half * 8;
            float acc[8];
#pragma unroll
            for (int jj = 0; jj < 8; ++jj) acc[jj] = b2_s[j0 + jj];
#pragma unroll
            for (int ch = 0; ch < 8; ++ch) {
                int off = t * 128 + ((ch * 16) ^ ((t & 7) << 4));
                bf16x8 hv = *(const bf16x8*)((const char*)pkb + off);
#pragma unroll
                for (int e = 0; e < 8; ++e) {
                    float hf = bf2f(hv[e]);
                    int k = ch * 8 + e;
#pragma unroll
                    for (int jj = 0; jj < 8; ++jj)
                        acc[jj] = fmaf(hf, W2_s[k * 16 + j0 + jj], acc[jj]);
                }
            }
            float part = 0.f;
#pragma unroll
            for (int jj = 0; jj < 8; ++jj) part += sigmoidf_(acc[jj]) * W3_s[j0 + jj];
            part += __shfl_xor(part, 1);
            if (half == 0) {
                bool m = (seq_idx[b * TT + t] != 0);
                lg[t] = m ? (part + b3g[0]) : -1e9f;
            }
        }
    }
    __syncthreads();

    if (w == 0) {
        float a  = lg[lane];
        float bv = (lane + 64 < TT) ? lg[lane + 64] : -1e30f;
        float mx = fmaxf(a, bv);
#pragma unroll
        for (int s = 32; s; s >>= 1) mx = fmaxf(mx, __shfl_xor(mx, s));
        float ea = __expf(a - mx);
        float eb = (lane + 64 < TT) ? __expf(bv - mx) : 0.f;
        float sum = ea + eb;
#pragma unroll
        for (int s = 32; s; s >>= 1) sum += __shfl_xor(sum, s);
        float inv = 1.0f / sum;
        scores[b * TT + lane] = ea * inv;
        if (lane + 64 < TT) scores[b * TT + lane + 64] = eb * inv;
    }
}

// ---------------- aux loss: one block per b, 4 waves x 25 t ----------------
__global__ __launch_bounds__(256)
void k_aux(const short* __restrict__ seq_h, const int* __restrict__ seq_idx,
           const int* __restrict__ neg_idx, const float* __restrict__ emb_item,
           const float* __restrict__ emb_neg, float* aux_acc) {
    int b = blockIdx.x, tid = threadIdx.x;
    int w = tid >> 6, l = tid & 63;
    __shared__ float pnum[4], pden[4];
    float num = 0.0f, den = 0.0f;
    for (int i = 0; i < 25; ++i) {
        int t = w + i * 4;
        if (t >= TT - 1) break;   // only w==3,i==24 (t=99)
        int ip  = seq_idx[b * TT + t + 1];
        int in_ = neg_idx[b * TT + t + 1];
        float h = bf2f(seq_h[(size_t)b * (TT * 64) + t * 64 + l]);
        float dp = h * emb_item[(size_t)ip * 64 + l];
        float dn = h * emb_neg[(size_t)in_ * 64 + l];
#pragma unroll
        for (int s = 32; s; s >>= 1) { dp += __shfl_xor(dp, s); dn += __shfl_xor(dn, s); }
        if (l == 0 && ip != 0) {
            float pp = sigmoidf_(dp), pn = sigmoidf_(dn);
            num += __logf(pp + 1e-8f) + __logf(1.0f - pn + 1e-8f);
            den += 1.0f;
        }
    }
    if (l == 0) { pnum[w] = num; pden[w] = den; }
    __syncthreads();
    if (tid == 0) {
        atomicAdd(&aux_acc[0], pnum[0] + pnum[1] + pnum[2] + pnum[3]);
        atomicAdd(&aux_acc[1], pden[0] + pden[1] + pden[2] + pden[3]);
    }
}

// ---------------- final MLP (BN + 3x dice FFN + sigmoid head) + aux write ----------------
__global__ __launch_bounds__(256)
void k_mlp(const float* __restrict__ final_state, const float* __restrict__ target,
           const float* __restrict__ dense, const int* __restrict__ sparse,
           const float* __restrict__ emb_other,
           const float* __restrict__ bng, const float* __restrict__ bnb,
           const float* __restrict__ W0, const float* __restrict__ bb0, const float* __restrict__ al0,
           const float* __restrict__ W1, const float* __restrict__ bb1, const float* __restrict__ al1,
           const float* __restrict__ W2, const float* __restrict__ bb2, const float* __restrict__ al2,
           const float* __restrict__ Wo, const float* __restrict__ bo,
           const float* __restrict__ aux_acc, float* __restrict__ out) {
    const float inv1 = 0.9995003747f;  // 1/sqrt(1+BN_EPS)
    int tid = threadIdx.x, b0 = blockIdx.x * 8;
    __shared__ float x_s[8][200], h1_s[8][256], h2_s[8][128], h3_s[8][64];

    for (int i = tid; i < 8 * 200; i += 256) {
        int r = i / 200, cc = i - r * 200, b = b0 + r;
        float v;
        if (cc < 64)       v = final_state[b * 64 + cc];
        else if (cc < 128) v = target[b * 64 + cc - 64];
        else if (cc < 136) v = dense[b * 8 + cc - 128];
        else if (cc < 168) v = emb_other[(size_t)sparse[b * 2 + 0] * 32 + (cc - 136)];
        else               v = emb_other[(size_t)10000 * 32 + (size_t)sparse[b * 2 + 1] * 32 + (cc - 168)];
        x_s[r][cc] = fmaf(bng[cc] * inv1, v, bnb[cc]);
    }
    __syncthreads();
    {   // L1: 200 -> 256, dice
        int r = tid >> 5, cb = tid & 31;
        float acc[8];
#pragma unroll
        for (int j = 0; j < 8; ++j) acc[j] = bb0[cb + 32 * j];
        for (int k = 0; k < 200; ++k) {
            float xv = x_s[r][k];
#pragma unroll
            for (int j = 0; j < 8; ++j) acc[j] = fmaf(xv, W0[k * 256 + cb + 32 * j], acc[j]);
        }
#pragma unroll
        for (int j = 0; j < 8; ++j) {
            float y = acc[j];
            float p = sigmoidf_(y * inv1);
            h1_s[r][cb + 32 * j] = y * (p + (1.0f - p) * al0[cb + 32 * j]);
        }
    }
    __syncthreads();
    {   // L2: 256 -> 128, dice
        int r = tid >> 5, cb = tid & 31;
        float acc[4];
#pragma unroll
        for (int j = 0; j < 4; ++j) acc[j] = bb1[cb + 32 * j];
        for (int k = 0; k < 256; ++k) {
            float xv = h1_s[r][k];
#pragma unroll
            for (int j = 0; j < 4; ++j) acc[j] = fmaf(xv, W1[k * 128 + cb + 32 * j], acc[j]);
        }
#pragma unroll
        for (int j = 0; j < 4; ++j) {
            float y = acc[j];
            float p = sigmoidf_(y * inv1);
            h2_s[r][cb + 32 * j] = y * (p + (1.0f - p) * al1[cb + 32 * j]);
        }
    }
    __syncthreads();
    {   // L3: 128 -> 64, dice
        int r = tid >> 5, cb = tid & 31;
        float acc[2] = {bb2[cb], bb2[cb + 32]};
        for (int k = 0; k < 128; ++k) {
            float xv = h2_s[r][k];
            acc[0] = fmaf(xv, W2[k * 64 + cb], acc[0]);
            acc[1] = fmaf(xv, W2[k * 64 + cb + 32], acc[1]);
        }
#pragma unroll
        for (int j = 0; j < 2; ++j) {
            float y = acc[j];
            float p = sigmoidf_(y * inv1);
            h3_s[r][cb + 32 * j] = y * (p + (1.0f - p) * al2[cb + 32 * j]);
        }
    }
    __syncthreads();
    {   // head: 64 -> 1 sigmoid
        int r = tid >> 5, l = tid & 31;
        float v = h3_s[r][l] * Wo[l] + h3_s[r][l + 32] * Wo[l + 32];
#pragma unroll
        for (int s = 16; s; s >>= 1) v += __shfl_xor(v, s, 32);
        if (l == 0) out[b0 + r] = sigmoidf_(v + bo[0]);
    }
    if (blockIdx.x == 0 && tid == 0) {
        out[BB] = -aux_acc[0] / (aux_acc[1] + 1e-8f);
    }
}

extern "C" void kernel_launch(void* const* d_in, const int* in_sizes, int n_in,
                              void* d_out, int out_size, void* d_ws, size_t ws_size,
                              hipStream_t stream) {
    (void)in_sizes; (void)n_in; (void)out_size; (void)ws_size;
    const float* dense    = (const float*)d_in[0];
    const int*   sparse   = (const int*)d_in[1];
    const int*   seq_in   = (const int*)d_in[2];
    const int*   neg_in   = (const int*)d_in[3];
    const int*   item_in  = (const int*)d_in[4];
    const int*   hist     = (const int*)d_in[5];
    const float* emb_item = (const float*)d_in[6];
    const float* emb_neg  = (const float*)d_in[7];
    const float* emb_oth  = (const float*)d_in[8];
    const float* g1Wx = (const float*)d_in[9];
    const float* g1Wh = (const float*)d_in[10];
    const float* g1b  = (const float*)d_in[11];
    const float* aW1  = (const float*)d_in[12];
    const float* ab1  = (const float*)d_in[13];
    const float* aW2  = (const float*)d_in[14];
    const float* ab2  = (const float*)d_in[15];
    const float* aW3  = (const float*)d_in[16];
    const float* ab3  = (const float*)d_in[17];
    const float* g2Wx = (const float*)d_in[18];
    const float* g2Wh = (const float*)d_in[19];
    const float* g2b  = (const float*)d_in[20];
    const float* bng  = (const float*)d_in[21];
    const float* bnb  = (const float*)d_in[22];
    const float* W0   = (const float*)d_in[23];
    const float* b0f  = (const float*)d_in[24];
    const float* a0f  = (const float*)d_in[25];
    const float* W1f  = (const float*)d_in[26];
    const float* b1f  = (const float*)d_in[27];
    const float* a1f  = (const float*)d_in[28];
    const float* W2f  = (const float*)d_in[29];
    const float* b2f  = (const float*)d_in[30];
    const float* a2f  = (const float*)d_in[31];
    const float* Wo   = (const float*)d_in[32];
    const float* bo   = (const float*)d_in[33];

    float* ws          = (float*)d_ws;
    short* seq_hb      = (short*)ws;              // B*T*64 shorts = 26,214,400 B
    float* scoresW     = ws + 6553600;            // B*T
    float* target      = scoresW + 204800;        // B*64
    float* qproj       = target + 131072;
    float* final_state = qproj + 131072;
    float* Wq          = final_state + 131072;    // 4096
    float* Wk          = Wq + 4096;
    float* Wp          = Wk + 4096;
    short* WxB1        = (short*)(Wp + 4096);     // 12288 shorts each
    short* WhB1        = WxB1 + 12288;
    short* WxB2        = WhB1 + 12288;
    short* WhB2        = WxB2 + 12288;
    short* WkB         = WhB2 + 12288;            // 4096 shorts
    short* WpB         = WkB + 4096;              // 4096 shorts
    float* aux_acc     = (float*)(WpB + 4096);    // 2 floats

    k_prep<<<16, 256, 0, stream>>>(aW1, Wq, Wk, Wp, aux_acc);
    k_prepW<<<dim3(48, 4), 256, 0, stream>>>(g1Wx, g1Wh, g2Wx, g2Wh, WxB1, WhB1, WxB2, WhB2);
    k_prepA<<<32, 256, 0, stream>>>(Wk, Wp, WkB, WpB);
    k_target<<<BB, 64, 0, stream>>>(item_in, emb_item, Wq, ab1, target, qproj);
    k_scan<0><<<512, 256, 0, stream>>>(seq_in, emb_item, nullptr, WxB1, WhB1, g1b, hist,
                                       nullptr, seq_hb, nullptr);
    k_attn<<<BB, 256, 0, stream>>>(seq_hb, target, qproj, seq_in, WkB, WpB, aW2, ab2, aW3, ab3, scoresW);
    k_scan<1><<<512, 256, 0, stream>>>(seq_in, nullptr, seq_hb, WxB2, WhB2, g2b, hist,
                                       scoresW, nullptr, final_state);
    k_aux<<<BB, 256, 0, stream>>>(seq_hb, seq_in, neg_in, emb_item, emb_neg, aux_acc);
    k_mlp<<<256, 256, 0, stream>>>(final_state, target, dense, sparse, emb_oth, bng, bnb,
                                   W0, b0f, a0f, W1f, b1f, a1f, W2f, b2f, a2f, Wo, bo,
                                   aux_acc, (float*)d_out);
}

// Round 6
// 519.140 us; speedup vs baseline: 3.6861x; 1.1522x over previous
//
#include <hip/hip_runtime.h>
#include <math.h>

// DIEN: B=2048 T=100 D=64.
// Round 6: 16-row scan blocks (all-lane gates), gather hoisted out of the serial loop.

#define DEV __device__ __forceinline__

constexpr int BB = 2048;
constexpr int TT = 100;

typedef __attribute__((ext_vector_type(8))) short bf16x8;
typedef __attribute__((ext_vector_type(4))) float f32x4;

#define MFMA16(a, b, c) __builtin_amdgcn_mfma_f32_16x16x32_bf16(a, b, c, 0, 0, 0)

DEV float sigmoidf_(float x) { return 1.0f / (1.0f + __expf(-x)); }
DEV float tanhf_(float x)    { return 1.0f - 2.0f / (__expf(2.0f * x) + 1.0f); }
DEV short f2bf(float f) {  // fp32 -> bf16 bits, round-to-nearest-even
    unsigned u = __float_as_uint(f);
    u = (u + 0x7FFFu + ((u >> 16) & 1u)) >> 16;
    return (short)u;
}
DEV float bf2f(short s) { return __uint_as_float(((unsigned)(unsigned short)s) << 16); }

// LDS-only barrier: does NOT drain vmcnt (global stores/loads keep flying).
DEV void sync_lds() {
    __builtin_amdgcn_sched_barrier(0);
    asm volatile("s_waitcnt lgkmcnt(0)\n\ts_barrier" ::: "memory");
    __builtin_amdgcn_sched_barrier(0);
}

// ---------------- prep: fold att_W1 into Wq/Wk/Wp; zero aux accumulator ----------------
__global__ void k_prep(const float* __restrict__ W1, float* Wq, float* Wk, float* Wp, float* aux_acc) {
    int i = blockIdx.x * 256 + threadIdx.x;
    if (i < 4096) {
        int k = i >> 6, c = i & 63;
        float a  = W1[k * 64 + c];
        float bb = W1[(64 + k) * 64 + c];
        float cc = W1[(128 + k) * 64 + c];
        float dd = W1[(192 + k) * 64 + c];
        Wq[i] = a + cc;
        Wk[i] = bb - cc;
        Wp[i] = dd;
    }
    if (blockIdx.x == 0 && threadIdx.x == 0) { aux_acc[0] = 0.0f; aux_acc[1] = 0.0f; }
}

// ---------------- prepW: pack GRU weights (64x192 fp32) into bf16 MFMA B-fragments ----
__global__ __launch_bounds__(256)
void k_prepW(const float* __restrict__ Wa, const float* __restrict__ Wb,
             const float* __restrict__ Wc, const float* __restrict__ Wd,
             short* __restrict__ oa, short* __restrict__ ob,
             short* __restrict__ oc, short* __restrict__ od) {
    const float* W; short* o;
    switch (blockIdx.y) {
        case 0:  W = Wa; o = oa; break;
        case 1:  W = Wb; o = ob; break;
        case 2:  W = Wc; o = oc; break;
        default: W = Wd; o = od; break;
    }
    int d = blockIdx.x * 256 + threadIdx.x;  // 48 blocks -> 12288
    int frag = d >> 9, l = (d >> 3) & 63, i = d & 7;
    int n = frag >> 1, kt = frag & 1;
    int k = kt * 32 + ((l >> 4) << 3) + i;
    int c = (n << 4) + (l & 15);
    o[d] = f2bf(W[k * 192 + c]);
}

// ---------------- prepA: pack Wk/Wp (64x64 fp32) into bf16 B-frags (f = kt*4+n) -------
__global__ __launch_bounds__(256)
void k_prepA(const float* __restrict__ Wk, const float* __restrict__ Wp,
             short* __restrict__ oK, short* __restrict__ oP) {
    int d = blockIdx.x * 256 + threadIdx.x;  // 32 blocks -> 8192
    int mat = d >> 12, i = d & 4095;
    int f = i >> 9, l = (i >> 3) & 63, e = i & 7;
    int kt = f >> 2, n = f & 3;
    int k = kt * 32 + ((l >> 4) << 3) + e;
    int c = (n << 4) + (l & 15);
    if (mat == 0) oK[i] = f2bf(Wk[k * 64 + c]);
    else          oP[i] = f2bf(Wp[k * 64 + c]);
}

// ---------------- target gather + qproj = q@Wq + b1 ----------------
__global__ __launch_bounds__(64)
void k_target(const int* __restrict__ item, const float* __restrict__ emb_item,
              const float* __restrict__ Wq, const float* __restrict__ b1,
              float* target, float* qproj) {
    int b = blockIdx.x, c = threadIdx.x;
    __shared__ float q[64];
    int idx = item[b];
    float tv = emb_item[(size_t)idx * 64 + c];
    target[b * 64 + c] = tv;
    q[c] = tv;
    __syncthreads();
    float acc = b1[c];
#pragma unroll
    for (int k = 0; k < 64; ++k) acc = fmaf(q[k], Wq[k * 64 + c], acc);
    qproj[b * 64 + c] = acc;
}

// ---------------- gather: e1b[b][t][64] = bf16(emb_item[seq_idx[b][t]]) --------------
__global__ __launch_bounds__(256)
void k_gather(const int* __restrict__ seq_idx, const float* __restrict__ emb,
              short* __restrict__ out) {
    int g = blockIdx.x * 256 + threadIdx.x;   // 3200 blocks -> 819200
    int row = g >> 2, q = g & 3;              // row < 204800, q: 16-col quarter
    int idx = seq_idx[row];
    const float4* src = (const float4*)(emb + (size_t)idx * 64 + q * 16);
    float4 f0 = src[0], f1 = src[1], f2 = src[2], f3 = src[3];
    bf16x8 o0, o1;
    o0[0] = f2bf(f0.x); o0[1] = f2bf(f0.y); o0[2] = f2bf(f0.z); o0[3] = f2bf(f0.w);
    o0[4] = f2bf(f1.x); o0[5] = f2bf(f1.y); o0[6] = f2bf(f1.z); o0[7] = f2bf(f1.w);
    o1[0] = f2bf(f2.x); o1[1] = f2bf(f2.y); o1[2] = f2bf(f2.z); o1[3] = f2bf(f2.w);
    o1[4] = f2bf(f3.x); o1[5] = f2bf(f3.y); o1[6] = f2bf(f3.z); o1[7] = f2bf(f3.w);
    short* dst = out + (size_t)row * 64 + q * 16;
    *(bf16x8*)dst = o0;
    *(bf16x8*)(dst + 8) = o1;
}

// ---------------- MFMA GRU / AUGRU scan: 16 batch rows per block, 128 blocks ----------
// All 16 C-fragment rows are real => gates on all 64 lanes, no load duplication.
// e input is pre-gathered bf16 (esrc); per step: 2 prefetched bf16x8 loads + 12 MFMA.
template <int MODE>  // 0 = GRU1 (write bf16 seq_out), 1 = AUGRU (scores, write final_out)
__global__ __launch_bounds__(256)
void k_scan(const short* __restrict__ esrc,
            const short* __restrict__ WxB, const short* __restrict__ WhB,
            const float* __restrict__ bias, const int* __restrict__ hist_len,
            const float* __restrict__ scores,
            short* __restrict__ seq_out, float* __restrict__ final_out) {
    __shared__ short hA[2][1024];  // [buf][row*64 + swz], 16 rows x 64 cols bf16

    const int tid  = threadIdx.x;
    const int w    = tid >> 6;
    const int lane = tid & 63;
    const int lr   = lane & 15;
    const int kg   = lane >> 4;
    const int b0   = blockIdx.x * 16;

    for (int i = tid; i < 2048; i += 256) ((short*)hA)[i] = 0;

    // weight B-fragments in registers for the whole scan (n = w + n3*4: z/r/hh col-tiles)
    bf16x8 bx[3][2], bh[3][2];
#pragma unroll
    for (int n3 = 0; n3 < 3; ++n3) {
        int n = w + n3 * 4;
#pragma unroll
        for (int kt = 0; kt < 2; ++kt) {
            bx[n3][kt] = *(const bf16x8*)(WxB + (((n * 2 + kt) * 64 + lane) << 3));
            bh[n3][kt] = *(const bf16x8*)(WhB + (((n * 2 + kt) * 64 + lane) << 3));
        }
    }

    const int   c0  = (w << 4) + lr;
    const float bz  = bias[c0];
    const float brr = bias[64 + c0];
    const float bhb = bias[128 + c0];

    int   hist[4];
    float h[4] = {0.f, 0.f, 0.f, 0.f};
#pragma unroll
    for (int j = 0; j < 4; ++j) hist[j] = hist_len[b0 + kg * 4 + j];

    const size_t erow = (size_t)(b0 + lr) * TT * 64;   // + t*64 + {kg*8, 32+kg*8}
    bf16x8 e0 = *(const bf16x8*)(esrc + erow + kg * 8);
    bf16x8 e1 = *(const bf16x8*)(esrc + erow + 32 + kg * 8);
    float scc[4] = {1.f, 1.f, 1.f, 1.f};
    if (MODE == 1) {
#pragma unroll
        for (int j = 0; j < 4; ++j) scc[j] = scores[(b0 + kg * 4 + j) * TT];
    }
    __syncthreads();

    const int so0 = lr * 64 + (((kg    ) ^ (lr & 7)) << 3);
    const int so1 = lr * 64 + (((4 + kg) ^ (lr & 7)) << 3);

    for (int t = 0; t < TT; ++t) {
        const int buf = t & 1;
        bf16x8 ha0 = *(const bf16x8*)&hA[buf][so0];
        bf16x8 ha1 = *(const bf16x8*)&hA[buf][so1];

        // prefetch next step's e (and scores)
        bf16x8 n0, n1;
        float scn[4];
        const bool haven = (t < TT - 1);
        if (haven) {
            n0 = *(const bf16x8*)(esrc + erow + (size_t)(t + 1) * 64 + kg * 8);
            n1 = *(const bf16x8*)(esrc + erow + (size_t)(t + 1) * 64 + 32 + kg * 8);
            if (MODE == 1) {
#pragma unroll
                for (int j = 0; j < 4; ++j) scn[j] = scores[(b0 + kg * 4 + j) * TT + t + 1];
            }
        }

        f32x4 az  = {0.f, 0.f, 0.f, 0.f};
        f32x4 ar  = {0.f, 0.f, 0.f, 0.f};
        f32x4 ahx = {0.f, 0.f, 0.f, 0.f};
        f32x4 ahh = {0.f, 0.f, 0.f, 0.f};
        az  = MFMA16(e0,  bx[0][0], az);  az  = MFMA16(e1,  bx[0][1], az);
        az  = MFMA16(ha0, bh[0][0], az);  az  = MFMA16(ha1, bh[0][1], az);
        ar  = MFMA16(e0,  bx[1][0], ar);  ar  = MFMA16(e1,  bx[1][1], ar);
        ar  = MFMA16(ha0, bh[1][0], ar);  ar  = MFMA16(ha1, bh[1][1], ar);
        ahx = MFMA16(e0,  bx[2][0], ahx); ahx = MFMA16(e1,  bx[2][1], ahx);
        ahh = MFMA16(ha0, bh[2][0], ahh); ahh = MFMA16(ha1, bh[2][1], ahh);

        // gates: every lane owns 4 real rows (kg*4+j) at col c0
#pragma unroll
        for (int j = 0; j < 4; ++j) {
            int rr = kg * 4 + j;
            float a01  = (MODE == 1) ? scc[j] : 1.0f;
            float z    = sigmoidf_(az[j] + bz) * a01;
            float r    = sigmoidf_(ar[j] + brr);
            float cand = tanhf_(ahx[j] + bhb + r * ahh[j]);
            float hn   = h[j] + z * (cand - h[j]);
            h[j] = (t < hist[j]) ? hn : h[j];
            short v = f2bf(h[j]);
            hA[buf ^ 1][rr * 64 + ((((c0 >> 3)) ^ (rr & 7)) << 3) + (c0 & 7)] = v;
            if (MODE == 0)
                seq_out[((size_t)(b0 + rr) * TT + t) * 64 + c0] = v;
        }

        if (haven) {
            e0 = n0; e1 = n1;
            if (MODE == 1) {
#pragma unroll
                for (int j = 0; j < 4; ++j) scc[j] = scn[j];
            }
        }
        sync_lds();
    }

    if (MODE == 1) {
#pragma unroll
        for (int j = 0; j < 4; ++j)
            final_out[(b0 + kg * 4 + j) * 64 + c0] = h[j];
    }
}

// ---------------- MFMA attention: one block per b (bf16 seq_h input) ----------------
__global__ __launch_bounds__(256)
void k_attn(const short* __restrict__ seq_h, const float* __restrict__ target,
            const float* __restrict__ qproj, const int* __restrict__ seq_idx,
            const short* __restrict__ WkB, const short* __restrict__ WpB,
            const float* __restrict__ W2g, const float* __restrict__ b2g,
            const float* __restrict__ W3g, const float* __restrict__ b3g,
            float* __restrict__ scores) {
    __shared__ __align__(16) short keysb[7168];  // 112 x 64 bf16, XOR-swizzled
    __shared__ __align__(16) short pkb[7168];    // pk; h1 overwrites in phase A
    __shared__ float W2_s[1024];
    __shared__ float q_s[64], qp_s[64];
    __shared__ float b2_s[16], W3_s[16];
    __shared__ float lg[112];

    const int b = blockIdx.x, tid = threadIdx.x;
    const int w = tid >> 6, lane = tid & 63;

    bf16x8 BK[2][4], BP[2][4];
#pragma unroll
    for (int kt = 0; kt < 2; ++kt)
#pragma unroll
        for (int n = 0; n < 4; ++n) {
            BK[kt][n] = *(const bf16x8*)(WkB + (((kt * 4 + n) * 64 + lane) << 3));
            BP[kt][n] = *(const bf16x8*)(WpB + (((kt * 4 + n) * 64 + lane) << 3));
        }
    if (tid < 64)  { q_s[tid] = target[b * 64 + tid]; qp_s[tid] = qproj[b * 64 + tid]; }
    if (tid >= 64 && tid < 80) { b2_s[tid - 64] = b2g[tid - 64]; W3_s[tid - 64] = W3g[tid - 64]; }
    for (int i = tid; i < 1024; i += 256) W2_s[i] = W2g[i];
    __syncthreads();

    // stage keys + pk (bf16 source)
    for (int i4 = tid; i4 < 1792; i4 += 256) {
        int r = i4 >> 4, c4 = i4 & 15;
        short4 kv, pv;
        if (r < TT) {
            short4 sv = *(const short4*)(seq_h + (size_t)b * (TT * 64) + r * 64 + c4 * 4);
            float q0 = q_s[c4 * 4], q1 = q_s[c4 * 4 + 1], q2 = q_s[c4 * 4 + 2], q3 = q_s[c4 * 4 + 3];
            kv = sv;
            pv = make_short4(f2bf(bf2f(sv.x) * q0), f2bf(bf2f(sv.y) * q1),
                             f2bf(bf2f(sv.z) * q2), f2bf(bf2f(sv.w) * q3));
        } else {
            kv = make_short4(0, 0, 0, 0); pv = kv;
        }
        int off = r * 128 + ((c4 * 8) ^ ((r & 7) << 4));
        *(short4*)((char*)keysb + off) = kv;
        *(short4*)((char*)pkb + off)   = pv;
    }
    __syncthreads();

    // Phase A: 7 row-tiles of 16; wave w does rt = w, w+4
    for (int rt = w; rt < 7; rt += 4) {
        const int r0 = rt * 16;
        const int arow = r0 + (lane & 15);
        const int kb = lane >> 4;
        bf16x8 AK[2], AP[2];
#pragma unroll
        for (int kt = 0; kt < 2; ++kt) {
            int off = arow * 128 + (((kt * 64) + kb * 16) ^ ((arow & 7) << 4));
            AK[kt] = *(const bf16x8*)((const char*)keysb + off);
            AP[kt] = *(const bf16x8*)((const char*)pkb + off);
        }
        f32x4 C[4];
#pragma unroll
        for (int n = 0; n < 4; ++n) { C[n] = (f32x4){0.f, 0.f, 0.f, 0.f}; }
#pragma unroll
        for (int n = 0; n < 4; ++n) {
            C[n] = MFMA16(AK[0], BK[0][n], C[n]);
            C[n] = MFMA16(AK[1], BK[1][n], C[n]);
            C[n] = MFMA16(AP[0], BP[0][n], C[n]);
            C[n] = MFMA16(AP[1], BP[1][n], C[n]);
        }
#pragma unroll
        for (int n = 0; n < 4; ++n) {
            int col = n * 16 + (lane & 15);
            float qp = qp_s[col];
#pragma unroll
            for (int j = 0; j < 4; ++j) {
                int row = r0 + (lane >> 4) * 4 + j;
                float h1 = sigmoidf_(C[n][j] + qp);
                int off = row * 128 + ((col * 2) ^ ((row & 7) << 4));
                *(short*)((char*)pkb + off) = f2bf(h1);
            }
        }
    }
    __syncthreads();

    // Phase B: logits. Pair (tid, tid^1) shares row t = tid>>1.
    {
        int t = tid >> 1, half = tid & 1;
        if (t < TT) {
            int j0 = half * 8;
            float acc[8];
#pragma unroll
            for (int jj = 0; jj < 8; ++jj) acc[jj] = b2_s[j0 + jj];
#pragma unroll
            for (int ch = 0; ch < 8; ++ch) {
                int off = t * 128 + ((ch * 16) ^ ((t & 7) << 4));
                bf16x8 hv = *(const bf16x8*)((const char*)pkb + off);
#pragma unroll
                for (int e = 0; e < 8; ++e) {
                    float hf = bf2f(hv[e]);
                    int k = ch * 8 + e;
#pragma unroll
                    for (int jj = 0; jj < 8; ++jj)
                        acc[jj] = fmaf(hf, W2_s[k * 16 + j0 + jj], acc[jj]);
                }
            }
            float part = 0.f;
#pragma unroll
            for (int jj = 0; jj < 8; ++jj) part += sigmoidf_(acc[jj]) * W3_s[j0 + jj];
            part += __shfl_xor(part, 1);
            if (half == 0) {
                bool m = (seq_idx[b * TT + t] != 0);
                lg[t] = m ? (part + b3g[0]) : -1e9f;
            }
        }
    }
    __syncthreads();

    if (w == 0) {
        float a  = lg[lane];
        float bv = (lane + 64 < TT) ? lg[lane + 64] : -1e30f;
        float mx = fmaxf(a, bv);
#pragma unroll
        for (int s = 32; s; s >>= 1) mx = fmaxf(mx, __shfl_xor(mx, s));
        float ea = __expf(a - mx);
        float eb = (lane + 64 < TT) ? __expf(bv - mx) : 0.f;
        float sum = ea + eb;
#pragma unroll
        for (int s = 32; s; s >>= 1) sum += __shfl_xor(sum, s);
        float inv = 1.0f / sum;
        scores[b * TT + lane] = ea * inv;
        if (lane + 64 < TT) scores[b * TT + lane + 64] = eb * inv;
    }
}

// ---------------- aux loss: one block per b, 4 waves x 25 t ----------------
__global__ __launch_bounds__(256)
void k_aux(const short* __restrict__ seq_h, const int* __restrict__ seq_idx,
           const int* __restrict__ neg_idx, const float* __restrict__ emb_item,
           const float* __restrict__ emb_neg, float* aux_acc) {
    int b = blockIdx.x, tid = threadIdx.x;
    int w = tid >> 6, l = tid & 63;
    __shared__ float pnum[4], pden[4];
    float num = 0.0f, den = 0.0f;
    for (int i = 0; i < 25; ++i) {
        int t = w + i * 4;
        if (t >= TT - 1) break;
        int ip  = seq_idx[b * TT + t + 1];
        int in_ = neg_idx[b * TT + t + 1];
        float h = bf2f(seq_h[(size_t)b * (TT * 64) + t * 64 + l]);
        float dp = h * emb_item[(size_t)ip * 64 + l];
        float dn = h * emb_neg[(size_t)in_ * 64 + l];
#pragma unroll
        for (int s = 32; s; s >>= 1) { dp += __shfl_xor(dp, s); dn += __shfl_xor(dn, s); }
        if (l == 0 && ip != 0) {
            float pp = sigmoidf_(dp), pn = sigmoidf_(dn);
            num += __logf(pp + 1e-8f) + __logf(1.0f - pn + 1e-8f);
            den += 1.0f;
        }
    }
    if (l == 0) { pnum[w] = num; pden[w] = den; }
    __syncthreads();
    if (tid == 0) {
        atomicAdd(&aux_acc[0], pnum[0] + pnum[1] + pnum[2] + pnum[3]);
        atomicAdd(&aux_acc[1], pden[0] + pden[1] + pden[2] + pden[3]);
    }
}

// ---------------- final MLP (BN + 3x dice FFN + sigmoid head) + aux write ----------------
__global__ __launch_bounds__(256)
void k_mlp(const float* __restrict__ final_state, const float* __restrict__ target,
           const float* __restrict__ dense, const int* __restrict__ sparse,
           const float* __restrict__ emb_other,
           const float* __restrict__ bng, const float* __restrict__ bnb,
           const float* __restrict__ W0, const float* __restrict__ bb0, const float* __restrict__ al0,
           const float* __restrict__ W1, const float* __restrict__ bb1, const float* __restrict__ al1,
           const float* __restrict__ W2, const float* __restrict__ bb2, const float* __restrict__ al2,
           const float* __restrict__ Wo, const float* __restrict__ bo,
           const float* __restrict__ aux_acc, float* __restrict__ out) {
    const float inv1 = 0.9995003747f;  // 1/sqrt(1+BN_EPS)
    int tid = threadIdx.x, b0 = blockIdx.x * 8;
    __shared__ float x_s[8][200], h1_s[8][256], h2_s[8][128], h3_s[8][64];

    for (int i = tid; i < 8 * 200; i += 256) {
        int r = i / 200, cc = i - r * 200, b = b0 + r;
        float v;
        if (cc < 64)       v = final_state[b * 64 + cc];
        else if (cc < 128) v = target[b * 64 + cc - 64];
        else if (cc < 136) v = dense[b * 8 + cc - 128];
        else if (cc < 168) v = emb_other[(size_t)sparse[b * 2 + 0] * 32 + (cc - 136)];
        else               v = emb_other[(size_t)10000 * 32 + (size_t)sparse[b * 2 + 1] * 32 + (cc - 168)];
        x_s[r][cc] = fmaf(bng[cc] * inv1, v, bnb[cc]);
    }
    __syncthreads();
    {   // L1: 200 -> 256, dice
        int r = tid >> 5, cb = tid & 31;
        float acc[8];
#pragma unroll
        for (int j = 0; j < 8; ++j) acc[j] = bb0[cb + 32 * j];
        for (int k = 0; k < 200; ++k) {
            float xv = x_s[r][k];
#pragma unroll
            for (int j = 0; j < 8; ++j) acc[j] = fmaf(xv, W0[k * 256 + cb + 32 * j], acc[j]);
        }
#pragma unroll
        for (int j = 0; j < 8; ++j) {
            float y = acc[j];
            float p = sigmoidf_(y * inv1);
            h1_s[r][cb + 32 * j] = y * (p + (1.0f - p) * al0[cb + 32 * j]);
        }
    }
    __syncthreads();
    {   // L2: 256 -> 128, dice
        int r = tid >> 5, cb = tid & 31;
        float acc[4];
#pragma unroll
        for (int j = 0; j < 4; ++j) acc[j] = bb1[cb + 32 * j];
        for (int k = 0; k < 256; ++k) {
            float xv = h1_s[r][k];
#pragma unroll
            for (int j = 0; j < 4; ++j) acc[j] = fmaf(xv, W1[k * 128 + cb + 32 * j], acc[j]);
        }
#pragma unroll
        for (int j = 0; j < 4; ++j) {
            float y = acc[j];
            float p = sigmoidf_(y * inv1);
            h2_s[r][cb + 32 * j] = y * (p + (1.0f - p) * al1[cb + 32 * j]);
        }
    }
    __syncthreads();
    {   // L3: 128 -> 64, dice
        int r = tid >> 5, cb = tid & 31;
        float acc[2] = {bb2[cb], bb2[cb + 32]};
        for (int k = 0; k < 128; ++k) {
            float xv = h2_s[r][k];
            acc[0] = fmaf(xv, W2[k * 64 + cb], acc[0]);
            acc[1] = fmaf(xv, W2[k * 64 + cb + 32], acc[1]);
        }
#pragma unroll
        for (int j = 0; j < 2; ++j) {
            float y = acc[j];
            float p = sigmoidf_(y * inv1);
            h3_s[r][cb + 32 * j] = y * (p + (1.0f - p) * al2[cb + 32 * j]);
        }
    }
    __syncthreads();
    {   // head: 64 -> 1 sigmoid
        int r = tid >> 5, l = tid & 31;
        float v = h3_s[r][l] * Wo[l] + h3_s[r][l + 32] * Wo[l + 32];
#pragma unroll
        for (int s = 16; s; s >>= 1) v += __shfl_xor(v, s, 32);
        if (l == 0) out[b0 + r] = sigmoidf_(v + bo[0]);
    }
    if (blockIdx.x == 0 && tid == 0) {
        out[BB] = -aux_acc[0] / (aux_acc[1] + 1e-8f);
    }
}

extern "C" void kernel_launch(void* const* d_in, const int* in_sizes, int n_in,
                              void* d_out, int out_size, void* d_ws, size_t ws_size,
                              hipStream_t stream) {
    (void)in_sizes; (void)n_in; (void)out_size; (void)ws_size;
    const float* dense    = (const float*)d_in[0];
    const int*   sparse   = (const int*)d_in[1];
    const int*   seq_in   = (const int*)d_in[2];
    const int*   neg_in   = (const int*)d_in[3];
    const int*   item_in  = (const int*)d_in[4];
    const int*   hist     = (const int*)d_in[5];
    const float* emb_item = (const float*)d_in[6];
    const float* emb_neg  = (const float*)d_in[7];
    const float* emb_oth  = (const float*)d_in[8];
    const float* g1Wx = (const float*)d_in[9];
    const float* g1Wh = (const float*)d_in[10];
    const float* g1b  = (const float*)d_in[11];
    const float* aW1  = (const float*)d_in[12];
    const float* ab1  = (const float*)d_in[13];
    const float* aW2  = (const float*)d_in[14];
    const float* ab2  = (const float*)d_in[15];
    const float* aW3  = (const float*)d_in[16];
    const float* ab3  = (const float*)d_in[17];
    const float* g2Wx = (const float*)d_in[18];
    const float* g2Wh = (const float*)d_in[19];
    const float* g2b  = (const float*)d_in[20];
    const float* bng  = (const float*)d_in[21];
    const float* bnb  = (const float*)d_in[22];
    const float* W0   = (const float*)d_in[23];
    const float* b0f  = (const float*)d_in[24];
    const float* a0f  = (const float*)d_in[25];
    const float* W1f  = (const float*)d_in[26];
    const float* b1f  = (const float*)d_in[27];
    const float* a1f  = (const float*)d_in[28];
    const float* W2f  = (const float*)d_in[29];
    const float* b2f  = (const float*)d_in[30];
    const float* a2f  = (const float*)d_in[31];
    const float* Wo   = (const float*)d_in[32];
    const float* bo   = (const float*)d_in[33];

    float* ws          = (float*)d_ws;
    short* seq_hb      = (short*)ws;              // B*T*64 shorts (26.2 MB)
    short* e1b         = (short*)(ws + 6553600);  // B*T*64 shorts (26.2 MB)
    float* scoresW     = ws + 13107200;           // B*T
    float* target      = scoresW + 204800;        // B*64
    float* qproj       = target + 131072;
    float* final_state = qproj + 131072;
    float* Wq          = final_state + 131072;    // 4096
    float* Wk          = Wq + 4096;
    float* Wp          = Wk + 4096;
    short* WxB1        = (short*)(Wp + 4096);     // 12288 shorts each
    short* WhB1        = WxB1 + 12288;
    short* WxB2        = WhB1 + 12288;
    short* WhB2        = WxB2 + 12288;
    short* WkB         = WhB2 + 12288;            // 4096 shorts
    short* WpB         = WkB + 4096;              // 4096 shorts
    float* aux_acc     = (float*)(WpB + 4096);    // 2 floats

    k_prep<<<16, 256, 0, stream>>>(aW1, Wq, Wk, Wp, aux_acc);
    k_prepW<<<dim3(48, 4), 256, 0, stream>>>(g1Wx, g1Wh, g2Wx, g2Wh, WxB1, WhB1, WxB2, WhB2);
    k_prepA<<<32, 256, 0, stream>>>(Wk, Wp, WkB, WpB);
    k_target<<<BB, 64, 0, stream>>>(item_in, emb_item, Wq, ab1, target, qproj);
    k_gather<<<3200, 256, 0, stream>>>(seq_in, emb_item, e1b);
    k_scan<0><<<128, 256, 0, stream>>>(e1b, WxB1, WhB1, g1b, hist, nullptr, seq_hb, nullptr);
    k_attn<<<BB, 256, 0, stream>>>(seq_hb, target, qproj, seq_in, WkB, WpB, aW2, ab2, aW3, ab3, scoresW);
    k_scan<1><<<128, 256, 0, stream>>>(seq_hb, WxB2, WhB2, g2b, hist, scoresW, nullptr, final_state);
    k_aux<<<BB, 256, 0, stream>>>(seq_hb, seq_in, neg_in, emb_item, emb_neg, aux_acc);
    k_mlp<<<256, 256, 0, stream>>>(final_state, target, dense, sparse, emb_oth, bng, bnb,
                                   W0, b0f, a0f, W1f, b1f, a1f, W2f, b2f, a2f, Wo, bo,
                                   aux_acc, (float*)d_out);
}

// Round 8
// 518.704 us; speedup vs baseline: 3.6892x; 1.0008x over previous
//
#include <hip/hip_runtime.h>
#include <math.h>

// DIEN: B=2048 T=100 D=64.
// Round 7 (resubmit): scan critical-path surgery — xproj(t+1) precomputed in the shadow
// of step t, h-dependent MFMA chain depth 4 -> 2, e prefetch distance 2.

#define DEV __device__ __forceinline__

constexpr int BB = 2048;
constexpr int TT = 100;

typedef __attribute__((ext_vector_type(8))) short bf16x8;
typedef __attribute__((ext_vector_type(4))) float f32x4;

#define MFMA16(a, b, c) __builtin_amdgcn_mfma_f32_16x16x32_bf16(a, b, c, 0, 0, 0)

DEV float sigmoidf_(float x) { return 1.0f / (1.0f + __expf(-x)); }
DEV float tanhf_(float x)    { return 1.0f - 2.0f / (__expf(2.0f * x) + 1.0f); }
DEV short f2bf(float f) {  // fp32 -> bf16 bits, round-to-nearest-even
    unsigned u = __float_as_uint(f);
    u = (u + 0x7FFFu + ((u >> 16) & 1u)) >> 16;
    return (short)u;
}
DEV float bf2f(short s) { return __uint_as_float(((unsigned)(unsigned short)s) << 16); }

// LDS-only barrier: does NOT drain vmcnt (global stores/loads keep flying).
DEV void sync_lds() {
    __builtin_amdgcn_sched_barrier(0);
    asm volatile("s_waitcnt lgkmcnt(0)\n\ts_barrier" ::: "memory");
    __builtin_amdgcn_sched_barrier(0);
}

// ---------------- prep: fold att_W1 into Wq/Wk/Wp; zero aux accumulator ----------------
__global__ void k_prep(const float* __restrict__ W1, float* Wq, float* Wk, float* Wp, float* aux_acc) {
    int i = blockIdx.x * 256 + threadIdx.x;
    if (i < 4096) {
        int k = i >> 6, c = i & 63;
        float a  = W1[k * 64 + c];
        float bb = W1[(64 + k) * 64 + c];
        float cc = W1[(128 + k) * 64 + c];
        float dd = W1[(192 + k) * 64 + c];
        Wq[i] = a + cc;
        Wk[i] = bb - cc;
        Wp[i] = dd;
    }
    if (blockIdx.x == 0 && threadIdx.x == 0) { aux_acc[0] = 0.0f; aux_acc[1] = 0.0f; }
}

// ---------------- prepW: pack GRU weights (64x192 fp32) into bf16 MFMA B-fragments ----
__global__ __launch_bounds__(256)
void k_prepW(const float* __restrict__ Wa, const float* __restrict__ Wb,
             const float* __restrict__ Wc, const float* __restrict__ Wd,
             short* __restrict__ oa, short* __restrict__ ob,
             short* __restrict__ oc, short* __restrict__ od) {
    const float* W; short* o;
    switch (blockIdx.y) {
        case 0:  W = Wa; o = oa; break;
        case 1:  W = Wb; o = ob; break;
        case 2:  W = Wc; o = oc; break;
        default: W = Wd; o = od; break;
    }
    int d = blockIdx.x * 256 + threadIdx.x;  // 48 blocks -> 12288
    int frag = d >> 9, l = (d >> 3) & 63, i = d & 7;
    int n = frag >> 1, kt = frag & 1;
    int k = kt * 32 + ((l >> 4) << 3) + i;
    int c = (n << 4) + (l & 15);
    o[d] = f2bf(W[k * 192 + c]);
}

// ---------------- prepA: pack Wk/Wp (64x64 fp32) into bf16 B-frags (f = kt*4+n) -------
__global__ __launch_bounds__(256)
void k_prepA(const float* __restrict__ Wk, const float* __restrict__ Wp,
             short* __restrict__ oK, short* __restrict__ oP) {
    int d = blockIdx.x * 256 + threadIdx.x;  // 32 blocks -> 8192
    int mat = d >> 12, i = d & 4095;
    int f = i >> 9, l = (i >> 3) & 63, e = i & 7;
    int kt = f >> 2, n = f & 3;
    int k = kt * 32 + ((l >> 4) << 3) + e;
    int c = (n << 4) + (l & 15);
    if (mat == 0) oK[i] = f2bf(Wk[k * 64 + c]);
    else          oP[i] = f2bf(Wp[k * 64 + c]);
}

// ---------------- target gather + qproj = q@Wq + b1 ----------------
__global__ __launch_bounds__(64)
void k_target(const int* __restrict__ item, const float* __restrict__ emb_item,
              const float* __restrict__ Wq, const float* __restrict__ b1,
              float* target, float* qproj) {
    int b = blockIdx.x, c = threadIdx.x;
    __shared__ float q[64];
    int idx = item[b];
    float tv = emb_item[(size_t)idx * 64 + c];
    target[b * 64 + c] = tv;
    q[c] = tv;
    __syncthreads();
    float acc = b1[c];
#pragma unroll
    for (int k = 0; k < 64; ++k) acc = fmaf(q[k], Wq[k * 64 + c], acc);
    qproj[b * 64 + c] = acc;
}

// ---------------- gather: e1b[b][t][64] = bf16(emb_item[seq_idx[b][t]]) --------------
__global__ __launch_bounds__(256)
void k_gather(const int* __restrict__ seq_idx, const float* __restrict__ emb,
              short* __restrict__ out) {
    int g = blockIdx.x * 256 + threadIdx.x;   // 3200 blocks -> 819200
    int row = g >> 2, q = g & 3;              // row < 204800, q: 16-col quarter
    int idx = seq_idx[row];
    const float4* src = (const float4*)(emb + (size_t)idx * 64 + q * 16);
    float4 f0 = src[0], f1 = src[1], f2 = src[2], f3 = src[3];
    bf16x8 o0, o1;
    o0[0] = f2bf(f0.x); o0[1] = f2bf(f0.y); o0[2] = f2bf(f0.z); o0[3] = f2bf(f0.w);
    o0[4] = f2bf(f1.x); o0[5] = f2bf(f1.y); o0[6] = f2bf(f1.z); o0[7] = f2bf(f1.w);
    o1[0] = f2bf(f2.x); o1[1] = f2bf(f2.y); o1[2] = f2bf(f2.z); o1[3] = f2bf(f2.w);
    o1[4] = f2bf(f3.x); o1[5] = f2bf(f3.y); o1[6] = f2bf(f3.z); o1[7] = f2bf(f3.w);
    short* dst = out + (size_t)row * 64 + q * 16;
    *(bf16x8*)dst = o0;
    *(bf16x8*)(dst + 8) = o1;
}

// ---------------- MFMA GRU / AUGRU scan: 16 batch rows per block, 128 blocks ----------
// Pipelined: xproj(t+1) (e-only MFMAs, bias in C-init) computed during step t;
// in-step h-dependent chain is only 2 MFMAs deep. e prefetched 2 steps ahead.
template <int MODE>  // 0 = GRU1 (write bf16 seq_out), 1 = AUGRU (scores, write final_out)
__global__ __launch_bounds__(256)
void k_scan(const short* __restrict__ esrc,
            const short* __restrict__ WxB, const short* __restrict__ WhB,
            const float* __restrict__ bias, const int* __restrict__ hist_len,
            const float* __restrict__ scores,
            short* __restrict__ seq_out, float* __restrict__ final_out) {
    __shared__ short hA[2][1024];  // [buf][row*64 + swz], 16 rows x 64 cols bf16

    const int tid  = threadIdx.x;
    const int w    = tid >> 6;
    const int lane = tid & 63;
    const int lr   = lane & 15;
    const int kg   = lane >> 4;
    const int b0   = blockIdx.x * 16;

    for (int i = tid; i < 2048; i += 256) ((short*)hA)[i] = 0;

    // weight B-fragments in registers for the whole scan (n = w + n3*4: z/r/hh col-tiles)
    bf16x8 bx[3][2], bh[3][2];
#pragma unroll
    for (int n3 = 0; n3 < 3; ++n3) {
        int n = w + n3 * 4;
#pragma unroll
        for (int kt = 0; kt < 2; ++kt) {
            bx[n3][kt] = *(const bf16x8*)(WxB + (((n * 2 + kt) * 64 + lane) << 3));
            bh[n3][kt] = *(const bf16x8*)(WhB + (((n * 2 + kt) * 64 + lane) << 3));
        }
    }

    const int   c0  = (w << 4) + lr;
    const float bz  = bias[c0];
    const float brr = bias[64 + c0];
    const float bhb = bias[128 + c0];

    int   hist[4];
    float h[4] = {0.f, 0.f, 0.f, 0.f};
#pragma unroll
    for (int j = 0; j < 4; ++j) hist[j] = hist_len[b0 + kg * 4 + j];

    const size_t erow = (size_t)(b0 + lr) * TT * 64;   // + t*64 + {kg*8, 32+kg*8}

    // prologue: e(0), e(1); xproj(0) with bias-initialized accumulators
    bf16x8 en0 = *(const bf16x8*)(esrc + erow + 64 + kg * 8);        // e(1)
    bf16x8 en1 = *(const bf16x8*)(esrc + erow + 64 + 32 + kg * 8);
    f32x4 xz, xr, xh;
    {
        bf16x8 ec0 = *(const bf16x8*)(esrc + erow + kg * 8);          // e(0)
        bf16x8 ec1 = *(const bf16x8*)(esrc + erow + 32 + kg * 8);
        xz = (f32x4){bz, bz, bz, bz};
        xr = (f32x4){brr, brr, brr, brr};
        xh = (f32x4){bhb, bhb, bhb, bhb};
        xz = MFMA16(ec0, bx[0][0], xz); xz = MFMA16(ec1, bx[0][1], xz);
        xr = MFMA16(ec0, bx[1][0], xr); xr = MFMA16(ec1, bx[1][1], xr);
        xh = MFMA16(ec0, bx[2][0], xh); xh = MFMA16(ec1, bx[2][1], xh);
    }
    float scc[4] = {1.f, 1.f, 1.f, 1.f};
    if (MODE == 1) {
#pragma unroll
        for (int j = 0; j < 4; ++j) scc[j] = scores[(b0 + kg * 4 + j) * TT];
    }
    __syncthreads();

    const int so0 = lr * 64 + (((kg    ) ^ (lr & 7)) << 3);
    const int so1 = lr * 64 + (((4 + kg) ^ (lr & 7)) << 3);

    for (int t = 0; t < TT; ++t) {
        const int buf = t & 1;
        // h A-fragments (this step's recurrence input)
        bf16x8 ha0 = *(const bf16x8*)&hA[buf][so0];
        bf16x8 ha1 = *(const bf16x8*)&hA[buf][so1];

        // prefetch e(t+2) and scores(t+1) — consumed next iteration
        bf16x8 e20, e21;
        float  scn[4];
        if (t + 2 < TT) {
            e20 = *(const bf16x8*)(esrc + erow + (size_t)(t + 2) * 64 + kg * 8);
            e21 = *(const bf16x8*)(esrc + erow + (size_t)(t + 2) * 64 + 32 + kg * 8);
        }
        if (MODE == 1 && t + 1 < TT) {
#pragma unroll
            for (int j = 0; j < 4; ++j) scn[j] = scores[(b0 + kg * 4 + j) * TT + t + 1];
        }

        // xproj(t+1) from en — independent of h, fills the ds_read shadow
        f32x4 nxz, nxr, nxh;
        if (t + 1 < TT) {
            nxz = (f32x4){bz, bz, bz, bz};
            nxr = (f32x4){brr, brr, brr, brr};
            nxh = (f32x4){bhb, bhb, bhb, bhb};
            nxz = MFMA16(en0, bx[0][0], nxz); nxz = MFMA16(en1, bx[0][1], nxz);
            nxr = MFMA16(en0, bx[1][0], nxr); nxr = MFMA16(en1, bx[1][1], nxr);
            nxh = MFMA16(en0, bx[2][0], nxh); nxh = MFMA16(en1, bx[2][1], nxh);
        }

        // h-dependent part: 2-deep chains only
        f32x4 azh = {0.f, 0.f, 0.f, 0.f};
        f32x4 arh = {0.f, 0.f, 0.f, 0.f};
        f32x4 ahh = {0.f, 0.f, 0.f, 0.f};
        azh = MFMA16(ha0, bh[0][0], azh); azh = MFMA16(ha1, bh[0][1], azh);
        arh = MFMA16(ha0, bh[1][0], arh); arh = MFMA16(ha1, bh[1][1], arh);
        ahh = MFMA16(ha0, bh[2][0], ahh); ahh = MFMA16(ha1, bh[2][1], ahh);

        // gates: every lane owns 4 real rows (kg*4+j) at col c0
#pragma unroll
        for (int j = 0; j < 4; ++j) {
            int rr = kg * 4 + j;
            float a01  = (MODE == 1) ? scc[j] : 1.0f;
            float z    = sigmoidf_(xz[j] + azh[j]) * a01;
            float r    = sigmoidf_(xr[j] + arh[j]);
            float cand = tanhf_(fmaf(r, ahh[j], xh[j]));
            float hn   = h[j] + z * (cand - h[j]);
            h[j] = (t < hist[j]) ? hn : h[j];
            short v = f2bf(h[j]);
            hA[buf ^ 1][rr * 64 + ((((c0 >> 3)) ^ (rr & 7)) << 3) + (c0 & 7)] = v;
            if (MODE == 0)
                seq_out[((size_t)(b0 + rr) * TT + t) * 64 + c0] = v;
        }

        // rotate pipeline registers
        if (t + 1 < TT) {
            xz = nxz; xr = nxr; xh = nxh;
            en0 = e20; en1 = e21;   // e(t+2) becomes next iteration's en (t+1 shifted)
            if (MODE == 1) {
#pragma unroll
                for (int j = 0; j < 4; ++j) scc[j] = scn[j];
            }
        }
        sync_lds();
    }

    if (MODE == 1) {
#pragma unroll
        for (int j = 0; j < 4; ++j)
            final_out[(b0 + kg * 4 + j) * 64 + c0] = h[j];
    }
}

// ---------------- MFMA attention: one block per b (bf16 seq_h input) ----------------
__global__ __launch_bounds__(256)
void k_attn(const short* __restrict__ seq_h, const float* __restrict__ target,
            const float* __restrict__ qproj, const int* __restrict__ seq_idx,
            const short* __restrict__ WkB, const short* __restrict__ WpB,
            const float* __restrict__ W2g, const float* __restrict__ b2g,
            const float* __restrict__ W3g, const float* __restrict__ b3g,
            float* __restrict__ scores) {
    __shared__ __align__(16) short keysb[7168];  // 112 x 64 bf16, XOR-swizzled
    __shared__ __align__(16) short pkb[7168];    // pk; h1 overwrites in phase A
    __shared__ float W2_s[1024];
    __shared__ float q_s[64], qp_s[64];
    __shared__ float b2_s[16], W3_s[16];
    __shared__ float lg[112];

    const int b = blockIdx.x, tid = threadIdx.x;
    const int w = tid >> 6, lane = tid & 63;

    bf16x8 BK[2][4], BP[2][4];
#pragma unroll
    for (int kt = 0; kt < 2; ++kt)
#pragma unroll
        for (int n = 0; n < 4; ++n) {
            BK[kt][n] = *(const bf16x8*)(WkB + (((kt * 4 + n) * 64 + lane) << 3));
            BP[kt][n] = *(const bf16x8*)(WpB + (((kt * 4 + n) * 64 + lane) << 3));
        }
    if (tid < 64)  { q_s[tid] = target[b * 64 + tid]; qp_s[tid] = qproj[b * 64 + tid]; }
    if (tid >= 64 && tid < 80) { b2_s[tid - 64] = b2g[tid - 64]; W3_s[tid - 64] = W3g[tid - 64]; }
    for (int i = tid; i < 1024; i += 256) W2_s[i] = W2g[i];
    __syncthreads();

    // stage keys + pk (bf16 source)
    for (int i4 = tid; i4 < 1792; i4 += 256) {
        int r = i4 >> 4, c4 = i4 & 15;
        short4 kv, pv;
        if (r < TT) {
            short4 sv = *(const short4*)(seq_h + (size_t)b * (TT * 64) + r * 64 + c4 * 4);
            float q0 = q_s[c4 * 4], q1 = q_s[c4 * 4 + 1], q2 = q_s[c4 * 4 + 2], q3 = q_s[c4 * 4 + 3];
            kv = sv;
            pv = make_short4(f2bf(bf2f(sv.x) * q0), f2bf(bf2f(sv.y) * q1),
                             f2bf(bf2f(sv.z) * q2), f2bf(bf2f(sv.w) * q3));
        } else {
            kv = make_short4(0, 0, 0, 0); pv = kv;
        }
        int off = r * 128 + ((c4 * 8) ^ ((r & 7) << 4));
        *(short4*)((char*)keysb + off) = kv;
        *(short4*)((char*)pkb + off)   = pv;
    }
    __syncthreads();

    // Phase A: 7 row-tiles of 16; wave w does rt = w, w+4
    for (int rt = w; rt < 7; rt += 4) {
        const int r0 = rt * 16;
        const int arow = r0 + (lane & 15);
        const int kb = lane >> 4;
        bf16x8 AK[2], AP[2];
#pragma unroll
        for (int kt = 0; kt < 2; ++kt) {
            int off = arow * 128 + (((kt * 64) + kb * 16) ^ ((arow & 7) << 4));
            AK[kt] = *(const bf16x8*)((const char*)keysb + off);
            AP[kt] = *(const bf16x8*)((const char*)pkb + off);
        }
        f32x4 C[4];
#pragma unroll
        for (int n = 0; n < 4; ++n) { C[n] = (f32x4){0.f, 0.f, 0.f, 0.f}; }
#pragma unroll
        for (int n = 0; n < 4; ++n) {
            C[n] = MFMA16(AK[0], BK[0][n], C[n]);
            C[n] = MFMA16(AK[1], BK[1][n], C[n]);
            C[n] = MFMA16(AP[0], BP[0][n], C[n]);
            C[n] = MFMA16(AP[1], BP[1][n], C[n]);
        }
#pragma unroll
        for (int n = 0; n < 4; ++n) {
            int col = n * 16 + (lane & 15);
            float qp = qp_s[col];
#pragma unroll
            for (int j = 0; j < 4; ++j) {
                int row = r0 + (lane >> 4) * 4 + j;
                float h1 = sigmoidf_(C[n][j] + qp);
                int off = row * 128 + ((col * 2) ^ ((row & 7) << 4));
                *(short*)((char*)pkb + off) = f2bf(h1);
            }
        }
    }
    __syncthreads();

    // Phase B: logits. Pair (tid, tid^1) shares row t = tid>>1.
    {
        int t = tid >> 1, half = tid & 1;
        if (t < TT) {
            int j0 = half * 8;
            float acc[8];
#pragma unroll
            for (int jj = 0; jj < 8; ++jj) acc[jj] = b2_s[j0 + jj];
#pragma unroll
            for (int ch = 0; ch < 8; ++ch) {
                int off = t * 128 + ((ch * 16) ^ ((t & 7) << 4));
                bf16x8 hv = *(const bf16x8*)((const char*)pkb + off);
#pragma unroll
                for (int e = 0; e < 8; ++e) {
                    float hf = bf2f(hv[e]);
                    int k = ch * 8 + e;
#pragma unroll
                    for (int jj = 0; jj < 8; ++jj)
                        acc[jj] = fmaf(hf, W2_s[k * 16 + j0 + jj], acc[jj]);
                }
            }
            float part = 0.f;
#pragma unroll
            for (int jj = 0; jj < 8; ++jj) part += sigmoidf_(acc[jj]) * W3_s[j0 + jj];
            part += __shfl_xor(part, 1);
            if (half == 0) {
                bool m = (seq_idx[b * TT + t] != 0);
                lg[t] = m ? (part + b3g[0]) : -1e9f;
            }
        }
    }
    __syncthreads();

    if (w == 0) {
        float a  = lg[lane];
        float bv = (lane + 64 < TT) ? lg[lane + 64] : -1e30f;
        float mx = fmaxf(a, bv);
#pragma unroll
        for (int s = 32; s; s >>= 1) mx = fmaxf(mx, __shfl_xor(mx, s));
        float ea = __expf(a - mx);
        float eb = (lane + 64 < TT) ? __expf(bv - mx) : 0.f;
        float sum = ea + eb;
#pragma unroll
        for (int s = 32; s; s >>= 1) sum += __shfl_xor(sum, s);
        float inv = 1.0f / sum;
        scores[b * TT + lane] = ea * inv;
        if (lane + 64 < TT) scores[b * TT + lane + 64] = eb * inv;
    }
}

// ---------------- aux loss: one block per b, 4 waves x 25 t ----------------
__global__ __launch_bounds__(256)
void k_aux(const short* __restrict__ seq_h, const int* __restrict__ seq_idx,
           const int* __restrict__ neg_idx, const float* __restrict__ emb_item,
           const float* __restrict__ emb_neg, float* aux_acc) {
    int b = blockIdx.x, tid = threadIdx.x;
    int w = tid >> 6, l = tid & 63;
    __shared__ float pnum[4], pden[4];
    float num = 0.0f, den = 0.0f;
    for (int i = 0; i < 25; ++i) {
        int t = w + i * 4;
        if (t >= TT - 1) break;
        int ip  = seq_idx[b * TT + t + 1];
        int in_ = neg_idx[b * TT + t + 1];
        float h = bf2f(seq_h[(size_t)b * (TT * 64) + t * 64 + l]);
        float dp = h * emb_item[(size_t)ip * 64 + l];
        float dn = h * emb_neg[(size_t)in_ * 64 + l];
#pragma unroll
        for (int s = 32; s; s >>= 1) { dp += __shfl_xor(dp, s); dn += __shfl_xor(dn, s); }
        if (l == 0 && ip != 0) {
            float pp = sigmoidf_(dp), pn = sigmoidf_(dn);
            num += __logf(pp + 1e-8f) + __logf(1.0f - pn + 1e-8f);
            den += 1.0f;
        }
    }
    if (l == 0) { pnum[w] = num; pden[w] = den; }
    __syncthreads();
    if (tid == 0) {
        atomicAdd(&aux_acc[0], pnum[0] + pnum[1] + pnum[2] + pnum[3]);
        atomicAdd(&aux_acc[1], pden[0] + pden[1] + pden[2] + pden[3]);
    }
}

// ---------------- final MLP (BN + 3x dice FFN + sigmoid head) + aux write ----------------
__global__ __launch_bounds__(256)
void k_mlp(const float* __restrict__ final_state, const float* __restrict__ target,
           const float* __restrict__ dense, const int* __restrict__ sparse,
           const float* __restrict__ emb_other,
           const float* __restrict__ bng, const float* __restrict__ bnb,
           const float* __restrict__ W0, const float* __restrict__ bb0, const float* __restrict__ al0,
           const float* __restrict__ W1, const float* __restrict__ bb1, const float* __restrict__ al1,
           const float* __restrict__ W2, const float* __restrict__ bb2, const float* __restrict__ al2,
           const float* __restrict__ Wo, const float* __restrict__ bo,
           const float* __restrict__ aux_acc, float* __restrict__ out) {
    const float inv1 = 0.9995003747f;  // 1/sqrt(1+BN_EPS)
    int tid = threadIdx.x, b0 = blockIdx.x * 8;
    __shared__ float x_s[8][200], h1_s[8][256], h2_s[8][128], h3_s[8][64];

    for (int i = tid; i < 8 * 200; i += 256) {
        int r = i / 200, cc = i - r * 200, b = b0 + r;
        float v;
        if (cc < 64)       v = final_state[b * 64 + cc];
        else if (cc < 128) v = target[b * 64 + cc - 64];
        else if (cc < 136) v = dense[b * 8 + cc - 128];
        else if (cc < 168) v = emb_other[(size_t)sparse[b * 2 + 0] * 32 + (cc - 136)];
        else               v = emb_other[(size_t)10000 * 32 + (size_t)sparse[b * 2 + 1] * 32 + (cc - 168)];
        x_s[r][cc] = fmaf(bng[cc] * inv1, v, bnb[cc]);
    }
    __syncthreads();
    {   // L1: 200 -> 256, dice
        int r = tid >> 5, cb = tid & 31;
        float acc[8];
#pragma unroll
        for (int j = 0; j < 8; ++j) acc[j] = bb0[cb + 32 * j];
        for (int k = 0; k < 200; ++k) {
            float xv = x_s[r][k];
#pragma unroll
            for (int j = 0; j < 8; ++j) acc[j] = fmaf(xv, W0[k * 256 + cb + 32 * j], acc[j]);
        }
#pragma unroll
        for (int j = 0; j < 8; ++j) {
            float y = acc[j];
            float p = sigmoidf_(y * inv1);
            h1_s[r][cb + 32 * j] = y * (p + (1.0f - p) * al0[cb + 32 * j]);
        }
    }
    __syncthreads();
    {   // L2: 256 -> 128, dice
        int r = tid >> 5, cb = tid & 31;
        float acc[4];
#pragma unroll
        for (int j = 0; j < 4; ++j) acc[j] = bb1[cb + 32 * j];
        for (int k = 0; k < 256; ++k) {
            float xv = h1_s[r][k];
#pragma unroll
            for (int j = 0; j < 4; ++j) acc[j] = fmaf(xv, W1[k * 128 + cb + 32 * j], acc[j]);
        }
#pragma unroll
        for (int j = 0; j < 4; ++j) {
            float y = acc[j];
            float p = sigmoidf_(y * inv1);
            h2_s[r][cb + 32 * j] = y * (p + (1.0f - p) * al1[cb + 32 * j]);
        }
    }
    __syncthreads();
    {   // L3: 128 -> 64, dice
        int r = tid >> 5, cb = tid & 31;
        float acc[2] = {bb2[cb], bb2[cb + 32]};
        for (int k = 0; k < 128; ++k) {
            float xv = h2_s[r][k];
            acc[0] = fmaf(xv, W2[k * 64 + cb], acc[0]);
            acc[1] = fmaf(xv, W2[k * 64 + cb + 32], acc[1]);
        }
#pragma unroll
        for (int j = 0; j < 2; ++j) {
            float y = acc[j];
            float p = sigmoidf_(y * inv1);
            h3_s[r][cb + 32 * j] = y * (p + (1.0f - p) * al2[cb + 32 * j]);
        }
    }
    __syncthreads();
    {   // head: 64 -> 1 sigmoid
        int r = tid >> 5, l = tid & 31;
        float v = h3_s[r][l] * Wo[l] + h3_s[r][l + 32] * Wo[l + 32];
#pragma unroll
        for (int s = 16; s; s >>= 1) v += __shfl_xor(v, s, 32);
        if (l == 0) out[b0 + r] = sigmoidf_(v + bo[0]);
    }
    if (blockIdx.x == 0 && tid == 0) {
        out[BB] = -aux_acc[0] / (aux_acc[1] + 1e-8f);
    }
}

extern "C" void kernel_launch(void* const* d_in, const int* in_sizes, int n_in,
                              void* d_out, int out_size, void* d_ws, size_t ws_size,
                              hipStream_t stream) {
    (void)in_sizes; (void)n_in; (void)out_size; (void)ws_size;
    const float* dense    = (const float*)d_in[0];
    const int*   sparse   = (const int*)d_in[1];
    const int*   seq_in   = (const int*)d_in[2];
    const int*   neg_in   = (const int*)d_in[3];
    const int*   item_in  = (const int*)d_in[4];
    const int*   hist     = (const int*)d_in[5];
    const float* emb_item = (const float*)d_in[6];
    const float* emb_neg  = (const float*)d_in[7];
    const float* emb_oth  = (const float*)d_in[8];
    const float* g1Wx = (const float*)d_in[9];
    const float* g1Wh = (const float*)d_in[10];
    const float* g1b  = (const float*)d_in[11];
    const float* aW1  = (const float*)d_in[12];
    const float* ab1  = (const float*)d_in[13];
    const float* aW2  = (const float*)d_in[14];
    const float* ab2  = (const float*)d_in[15];
    const float* aW3  = (const float*)d_in[16];
    const float* ab3  = (const float*)d_in[17];
    const float* g2Wx = (const float*)d_in[18];
    const float* g2Wh = (const float*)d_in[19];
    const float* g2b  = (const float*)d_in[20];
    const float* bng  = (const float*)d_in[21];
    const float* bnb  = (const float*)d_in[22];
    const float* W0   = (const float*)d_in[23];
    const float* b0f  = (const float*)d_in[24];
    const float* a0f  = (const float*)d_in[25];
    const float* W1f  = (const float*)d_in[26];
    const float* b1f  = (const float*)d_in[27];
    const float* a1f  = (const float*)d_in[28];
    const float* W2f  = (const float*)d_in[29];
    const float* b2f  = (const float*)d_in[30];
    const float* a2f  = (const float*)d_in[31];
    const float* Wo   = (const float*)d_in[32];
    const float* bo   = (const float*)d_in[33];

    float* ws          = (float*)d_ws;
    short* seq_hb      = (short*)ws;              // B*T*64 shorts (26.2 MB)
    short* e1b         = (short*)(ws + 6553600);  // B*T*64 shorts (26.2 MB)
    float* scoresW     = ws + 13107200;           // B*T
    float* target      = scoresW + 204800;        // B*64
    float* qproj       = target + 131072;
    float* final_state = qproj + 131072;
    float* Wq          = final_state + 131072;    // 4096
    float* Wk          = Wq + 4096;
    float* Wp          = Wk + 4096;
    short* WxB1        = (short*)(Wp + 4096);     // 12288 shorts each
    short* WhB1        = WxB1 + 12288;
    short* WxB2        = WhB1 + 12288;
    short* WhB2        = WxB2 + 12288;
    short* WkB         = WhB2 + 12288;            // 4096 shorts
    short* WpB         = WkB + 4096;              // 4096 shorts
    float* aux_acc     = (float*)(WpB + 4096);    // 2 floats

    k_prep<<<16, 256, 0, stream>>>(aW1, Wq, Wk, Wp, aux_acc);
    k_prepW<<<dim3(48, 4), 256, 0, stream>>>(g1Wx, g1Wh, g2Wx, g2Wh, WxB1, WhB1, WxB2, WhB2);
    k_prepA<<<32, 256, 0, stream>>>(Wk, Wp, WkB, WpB);
    k_target<<<BB, 64, 0, stream>>>(item_in, emb_item, Wq, ab1, target, qproj);
    k_gather<<<3200, 256, 0, stream>>>(seq_in, emb_item, e1b);
    k_scan<0><<<128, 256, 0, stream>>>(e1b, WxB1, WhB1, g1b, hist, nullptr, seq_hb, nullptr);
    k_attn<<<BB, 256, 0, stream>>>(seq_hb, target, qproj, seq_in, WkB, WpB, aW2, ab2, aW3, ab3, scoresW);
    k_scan<1><<<128, 256, 0, stream>>>(seq_hb, WxB2, WhB2, g2b, hist, scoresW, nullptr, final_state);
    k_aux<<<BB, 256, 0, stream>>>(seq_hb, seq_in, neg_in, emb_item, emb_neg, aux_acc);
    k_mlp<<<256, 256, 0, stream>>>(final_state, target, dense, sparse, emb_oth, bng, bnb,
                                   W0, b0f, a0f, W1f, b1f, a1f, W2f, b2f, a2f, Wo, bo,
                                   aux_acc, (float*)d_out);
}